// Round 1
// baseline (2679.858 us; speedup 1.0000x reference)
//
#include <hip/hip_runtime.h>
#include <hip/hip_cooperative_groups.h>
#include <math.h>

namespace cg = cooperative_groups;

#define S_LEN 16
#define BSZ   64
#define NN    10000
#define LAT   128
#define DH    257
#define KTAB  1024
#define CSTRIDE (KTAB + 8)    // costab leading dim
#define FSTRIDE (KTAB + 4)    // ftab leading dim
#define NTILE 64
#define NTILES 157            // ceil(10000/64)
#define NBLK  (NTILES + 128)  // 285 fused grid
#define SCALE 0.08838834764831845f
#define NEG1E9 -1000000000.0f

// ================= GRU one row with 256 threads, uses caller's 1028-float sm =================
__device__ __forceinline__ void do_gru_row256(int r, int tid2, int s, int zeroH,
    const float* __restrict__ x, const float* __restrict__ t,
    const int* __restrict__ source, const int* __restrict__ target,
    const float* __restrict__ tw, const float* __restrict__ tb_,
    const float* __restrict__ W_ihT, const float* __restrict__ W_hhT,
    const float* __restrict__ b_ih, const float* __restrict__ b_hh,
    const float* __restrict__ mem, float* __restrict__ newh, float* sm) {
    float* msg = sm;          // 132
    float* h   = sm + 132;    // 128
    float* gi3 = sm + 260;    // 384
    float* gh3 = sm + 644;    // 384
    int b = r & 63;
    int idx = (r < 64) ? source[s * BSZ + b] : target[s * BSZ + b];
    const float* xs = x + (size_t)(s * BSZ + b) * NN;
    const float* ts = t + (size_t)(s * BSZ + b) * NN;
    if (tid2 == 0) msg[0] = xs[idx];
    if (tid2 < 128) {
        float tv = ts[idx];
        msg[1 + tid2] = __cosf(tv * tw[tid2] + tb_[tid2]);
        h[tid2] = zeroH ? 0.f : mem[(size_t)idx * LAT + tid2];
    }
    __syncthreads();
    if (tid2 < 128) {
        int j = tid2;
        float a0 = b_ih[j], a1 = b_ih[128 + j], a2 = b_ih[256 + j];
#pragma unroll 4
        for (int d = 0; d < 129; ++d) {
            float m = msg[d];
            const float* col = W_ihT + d * 384;
            a0 += m * col[j]; a1 += m * col[128 + j]; a2 += m * col[256 + j];
        }
        gi3[j] = a0; gi3[128 + j] = a1; gi3[256 + j] = a2;
    } else {
        int j = tid2 - 128;
        float a0 = b_hh[j], a1 = b_hh[128 + j], a2 = b_hh[256 + j];
#pragma unroll 4
        for (int l = 0; l < 128; ++l) {
            float hv = h[l];
            const float* col = W_hhT + l * 384;
            a0 += hv * col[j]; a1 += hv * col[128 + j]; a2 += hv * col[256 + j];
        }
        gh3[j] = a0; gh3[128 + j] = a1; gh3[256 + j] = a2;
    }
    __syncthreads();
    if (tid2 < 128) {
        int j = tid2;
        float rr = 1.f / (1.f + __expf(-(gi3[j] + gh3[j])));
        float zz = 1.f / (1.f + __expf(-(gi3[128 + j] + gh3[128 + j])));
        float nn2 = tanhf(gi3[256 + j] + rr * gh3[256 + j]);
        newh[r * LAT + j] = (1.f - zz) * nn2 + zz * h[j];
    }
}

// ================= combine partials -> logit (tid<64) =================
__device__ __forceinline__ void do_combine(const float* __restrict__ partials,
                                           const float* __restrict__ vconst,
                                           float* __restrict__ out, int ps, int tid) {
    if (tid >= 64) return;
    int b = tid;
    float M = -3.0e38f, D = 0.f, Nm = 0.f;
    const float4* pp = (const float4*)partials + b * NTILES;
    for (int i = 0; i < NTILES; ++i) {
        float4 p = pp[i];
        float M2 = fmaxf(M, p.x);
        float e1 = __expf(M - M2), e2 = __expf(p.x - M2);
        D = D * e1 + p.y * e2;
        Nm = Nm * e1 + p.z * e2;
        M = M2;
    }
    out[ps * BSZ + b] = Nm / D + vconst[0];
}

// ============================================================================================
// Fused persistent cooperative kernel: setup + pre + 16x(A,B) + tail in ONE dispatch.
// ============================================================================================
struct KParams {
    const float *x, *t;
    const int *source, *target;
    const void *maskp;
    const float *tw, *tb_;
    const float *W_ih, *W_hh, *b_ih, *b_hh;
    const float *Wq, *bq, *Wk, *bk, *Wv, *bv, *W_out, *b_out;
    float *out;
    float *mem, *newh, *uT, *u0_g, *qbk_g, *ftab, *gtab, *costab, *partials;
    float *wv_out, *vconst, *W_ihT, *W_hhT, *BT, *uc, *kw0, *abk, *qconst, *scal;
    int *modep;
};

// ---- A-phase per-b work, 256 threads (K-splits are 2-way instead of step_a3's 4-way) ----
__device__ void a_work256(const KParams& p, float* sm, int b, int s) {
    float* memv  = sm;            // 128
    float* udt_s = sm + 128;      // 128
    float* upart = sm + 256;      // 2*260 = 520
    float* red   = sm + 776;      // 2 (room to 784)
    float* fpart = sm + 784;      // 1024 -> ends 1808
    float* xvs_p = sm + 1808;
    int*   slast_p = (int*)(sm + 1809);
    int tid = threadIdx.x;

    if (tid < 64) {
        unsigned long long mball = __ballot(p.target[s * BSZ + tid] == p.target[s * BSZ + b]);
        if (tid == 0) {
            *slast_p = 63 - __builtin_clzll(mball);
            *xvs_p = p.x[(size_t)(s * BSZ + b) * NN + p.target[s * BSZ + b]];
        }
    }
    __syncthreads();
    int s_last = *slast_p;
    if (tid < 128) memv[tid] = p.newh[(64 + s_last) * LAT + tid];   // post-scatter mem[tg]
    __syncthreads();
    float xv = *xvs_p;
    {   // u[d] = uc[d] + xv*kw0[d] + sum_l memv[l]*BT[l*260+d], K split 2 ways (chain 64)
        int dd = tid & 127, kc = tid >> 7;
        int l0 = kc * 64;
        for (int d = dd; d < DH; d += 128) {
            float a = 0.f;
#pragma unroll 4
            for (int l = l0; l < l0 + 64; ++l) a += memv[l] * p.BT[l * 260 + d];
            upart[kc * 260 + d] = a;
        }
    }
    __syncthreads();
    {
        float a = p.uc[tid] + xv * p.kw0[tid] + upart[tid] + upart[260 + tid];
        if (tid == 0) p.u0_g[b] = a;
        else if (tid <= 128) p.uT[(tid - 1) * BSZ + b] = a;
        else udt_s[tid - 129] = a;                 // d = 129..255 -> udt_s[0..126]
        if (tid == 0) {                            // d = 256 -> udt_s[127]
            float a2 = p.uc[256] + xv * p.kw0[256] + upart[256] + upart[516];
            udt_s[127] = a2;
        }
    }
    if (tid >= 192) {   // qbk = scal0 + xv*scal1 + memv.abk  (one wave: wave 3)
        int i = tid - 192;
        float a = memv[i] * p.abk[i] + memv[64 + i] * p.abk[64 + i];
        for (int off = 32; off; off >>= 1) a += __shfl_down(a, off, 64);
        if (i == 0) p.qbk_g[b] = p.scal[0] + xv * p.scal[1] + a;
    }
    __syncthreads();
    {   // ftab: 8 points/thread, L split 2 ways (chain 64)
        int pi = tid & 127, lc = tid >> 7;
        int l0 = lc * 64;
        float a0x = 0.f, a0y = 0.f, a0z = 0.f, a0w = 0.f;
        float a1x = 0.f, a1y = 0.f, a1z = 0.f, a1w = 0.f;
#pragma unroll 4
        for (int l = l0; l < l0 + 64; ++l) {
            float ul = udt_s[l];
            const float* cp = &p.costab[l * CSTRIDE + pi * 8];
            float4 c0 = *(const float4*)cp;
            float4 c1 = *(const float4*)(cp + 4);
            a0x += ul * c0.x; a0y += ul * c0.y; a0z += ul * c0.z; a0w += ul * c0.w;
            a1x += ul * c1.x; a1y += ul * c1.y; a1z += ul * c1.z; a1w += ul * c1.w;
        }
        if (lc) {
            float* fp = &fpart[pi * 8];
            *(float4*)fp = make_float4(a0x, a0y, a0z, a0w);
            *(float4*)(fp + 4) = make_float4(a1x, a1y, a1z, a1w);
        }
        if (pi == 127) {
            float a = 0.f;
            for (int l = l0; l < l0 + 64; ++l) a += udt_s[l] * p.costab[l * CSTRIDE + KTAB];
            red[lc] = a;
        }
        __syncthreads();
        if (lc == 0) {
            const float* fp = &fpart[pi * 8];
            a0x += fp[0]; a0y += fp[1]; a0z += fp[2]; a0w += fp[3];
            a1x += fp[4]; a1y += fp[5]; a1z += fp[6]; a1w += fp[7];
            float* fo = &p.ftab[b * FSTRIDE + pi * 8];
            *(float4*)fo = make_float4(a0x, a0y, a0z, a0w);
            *(float4*)(fo + 4) = make_float4(a1x, a1y, a1z, a1w);
        }
        if (tid == 0) p.ftab[b * FSTRIDE + KTAB] = red[0] + red[1];
    }
}

// ---- scatter, 256 threads (2 threads/row) ----
__device__ void scatter256(const KParams& p, float* sm, int s) {
    int* idxs  = (int*)sm;
    int* alive = idxs + 128;
    int tid = threadIdx.x;
    if (tid < 128) idxs[tid] = (tid < 64) ? p.source[s * BSZ + tid] : p.target[s * BSZ + (tid - 64)];
    __syncthreads();
    if (tid < 128) {
        int i2 = idxs[tid];
        int a = 1;
        for (int r2 = tid + 1; r2 < 128; ++r2)
            if (idxs[r2] == i2) { a = 0; break; }
        alive[tid] = a;
    }
    __syncthreads();
    int row = tid >> 1, q2 = tid & 1;
    if (alive[row]) {
        const float4* srcp = (const float4*)(p.newh + row * LAT + q2 * 64);
        float4* dstp = (float4*)(p.mem + (size_t)idxs[row] * LAT + q2 * 64);
#pragma unroll
        for (int j = 0; j < 16; ++j) dstp[j] = srcp[j];
    }
}

// ---- attention tile, 256 threads (verbatim from step_b2, shared carved from sm) ----
__device__ void attn_tile256(const KParams& p, float* sm, int tile, int s) {
    float* memT   = sm;           // 64*72 = 4608
    float* uTs    = sm + 4608;    // 64*68 = 4352
    float* memv_s = sm + 8960;    // 64
    float* wv_s   = sm + 9024;    // 128
    float* u0_s   = sm + 9152;    // 64
    float* qbk_s  = sm + 9216;    // 64  (total 9280)
    int tid = threadIdx.x;
    int n0 = tile * NTILE;
    int tb = tid >> 4, tn = tid & 15;
    int nvalid = NN - n0; if (nvalid > NTILE) nvalid = NTILE;

    if (tid < 128) wv_s[tid] = p.wv_out[1 + tid];
    if (tid < 64) { u0_s[tid] = p.u0_g[tid]; qbk_s[tid] = p.qbk_g[tid]; memv_s[tid] = 0.f; }

    float acc[4][4];
#pragma unroll
    for (int i = 0; i < 4; ++i)
#pragma unroll
        for (int j = 0; j < 4; ++j) acc[i][j] = 0.f;

    for (int l0 = 0; l0 < 128; l0 += 64) {
        __syncthreads();
        {   // stage mem -> memT transposed
            int n_l = tid & 63, lq = (tid >> 6) * 16;
            if (n_l < nvalid) {
                const float* mrow = p.mem + (size_t)(n0 + n_l) * LAT + l0 + lq;
                float4 a0 = *(const float4*)(mrow + 0);
                float4 a1 = *(const float4*)(mrow + 4);
                float4 a2 = *(const float4*)(mrow + 8);
                float4 a3 = *(const float4*)(mrow + 12);
                memT[(lq + 0) * 72 + n_l] = a0.x; memT[(lq + 1) * 72 + n_l] = a0.y;
                memT[(lq + 2) * 72 + n_l] = a0.z; memT[(lq + 3) * 72 + n_l] = a0.w;
                memT[(lq + 4) * 72 + n_l] = a1.x; memT[(lq + 5) * 72 + n_l] = a1.y;
                memT[(lq + 6) * 72 + n_l] = a1.z; memT[(lq + 7) * 72 + n_l] = a1.w;
                memT[(lq + 8) * 72 + n_l] = a2.x; memT[(lq + 9) * 72 + n_l] = a2.y;
                memT[(lq + 10) * 72 + n_l] = a2.z; memT[(lq + 11) * 72 + n_l] = a2.w;
                memT[(lq + 12) * 72 + n_l] = a3.x; memT[(lq + 13) * 72 + n_l] = a3.y;
                memT[(lq + 14) * 72 + n_l] = a3.z; memT[(lq + 15) * 72 + n_l] = a3.w;
            } else {
                for (int j = 0; j < 16; ++j) memT[(lq + j) * 72 + n_l] = 0.f;
            }
        }
        {   // stage uT chunk -> uTs
            int bq4 = (tid & 15) * 4;
            int ll = (tid >> 4) * 4;
            for (int j = 0; j < 4; ++j) {
                float4 v = *(const float4*)&p.uT[(l0 + ll + j) * BSZ + bq4];
                *(float4*)&uTs[(ll + j) * 68 + bq4] = v;
            }
        }
        __syncthreads();
        if (tid < 64) {   // memv partial
            float a = memv_s[tid];
            for (int l = 0; l < 64; ++l) a += wv_s[l0 + l] * memT[l * 72 + tid];
            memv_s[tid] = a;
        }
        for (int l = 0; l < 64; ++l) {
            float4 uv = *(const float4*)&uTs[l * 68 + tb * 4];
            float4 mv = *(const float4*)&memT[l * 72 + tn * 4];
            acc[0][0] += uv.x * mv.x; acc[0][1] += uv.x * mv.y; acc[0][2] += uv.x * mv.z; acc[0][3] += uv.x * mv.w;
            acc[1][0] += uv.y * mv.x; acc[1][1] += uv.y * mv.y; acc[1][2] += uv.y * mv.z; acc[1][3] += uv.y * mv.w;
            acc[2][0] += uv.z * mv.x; acc[2][1] += uv.z * mv.y; acc[2][2] += uv.z * mv.z; acc[2][3] += uv.z * mv.w;
            acc[3][0] += uv.w * mv.x; acc[3][1] += uv.w * mv.y; acc[3][2] += uv.w * mv.z; acc[3][3] += uv.w * mv.w;
        }
    }
    __syncthreads();

    const float c0 = p.wv_out[0];
    int mode = p.modep[0];
    const int* m32 = (const int*)p.maskp;
    const unsigned char* m8 = (const unsigned char*)p.maskp;
    const float* mf = (const float*)p.maskp;

    float pm[4], pd[4], pn[4];
#pragma unroll
    for (int i = 0; i < 4; ++i) { pm[i] = -3.0e38f; pd[i] = 0.f; pn[i] = 0.f; }

    for (int i = 0; i < 4; ++i) {
        int b = tb * 4 + i;
        size_t base = (size_t)(s * BSZ + b) * NN + n0 + tn * 4;
        float xv4[4], tv4[4]; int msk[4], vld[4];
        if (tn * 4 + 3 < nvalid) {
            float4 xx = *(const float4*)(p.x + base);
            float4 tt = *(const float4*)(p.t + base);
            xv4[0] = xx.x; xv4[1] = xx.y; xv4[2] = xx.z; xv4[3] = xx.w;
            tv4[0] = tt.x; tv4[1] = tt.y; tv4[2] = tt.z; tv4[3] = tt.w;
            if (mode == 1) {
                unsigned mw = *(const unsigned*)(m8 + base);
                msk[0] = mw & 0xff; msk[1] = (mw >> 8) & 0xff; msk[2] = (mw >> 16) & 0xff; msk[3] = (mw >> 24) & 0xff;
            } else if (mode == 2) {
                float4 mm = *(const float4*)(mf + base);
                msk[0] = (mm.x != 0.f); msk[1] = (mm.y != 0.f); msk[2] = (mm.z != 0.f); msk[3] = (mm.w != 0.f);
            } else {
                int4 mm = *(const int4*)(m32 + base);
                msk[0] = mm.x; msk[1] = mm.y; msk[2] = mm.z; msk[3] = mm.w;
            }
            vld[0] = vld[1] = vld[2] = vld[3] = 1;
        } else {
            for (int j = 0; j < 4; ++j) {
                int n = tn * 4 + j;
                vld[j] = (n < nvalid);
                if (vld[j]) {
                    xv4[j] = p.x[base + j]; tv4[j] = p.t[base + j];
                    msk[j] = (mode == 1) ? (int)m8[base + j] : (mode == 2) ? (mf[base + j] != 0.f) : m32[base + j];
                } else { xv4[j] = 0.f; tv4[j] = 0.f; msk[j] = 0; }
            }
        }
        const float* ft = p.ftab + b * FSTRIDE;
#pragma unroll
        for (int j = 0; j < 4; ++j) {
            if (!vld[j]) continue;
            float xv = xv4[j], tv = tv4[j];
            float pq = tv * (float)KTAB;
            pq = fminf(fmaxf(pq, 0.f), (float)KTAB - 0.001f);
            int ii = (int)pq;
            float fr = pq - (float)ii;
            float f0 = ft[ii];
            float fv = f0 + (ft[ii + 1] - f0) * fr;
            float g0 = p.gtab[ii];
            float gv = g0 + (p.gtab[ii + 1] - g0) * fr;
            float sc = SCALE * (xv * u0_s[b] + acc[i][j] + fv + qbk_s[b]);
            if (msk[j] == 0) sc = NEG1E9;
            float val = xv * c0 + memv_s[tn * 4 + j] + gv;
            if (sc > pm[i]) {
                float a = __expf(pm[i] - sc);
                pd[i] = pd[i] * a + 1.f;
                pn[i] = pn[i] * a + val;
                pm[i] = sc;
            } else {
                float e = __expf(sc - pm[i]);
                pd[i] += e;
                pn[i] += e * val;
            }
        }
    }
#pragma unroll
    for (int mk2 = 1; mk2 < 16; mk2 <<= 1) {
#pragma unroll
        for (int i = 0; i < 4; ++i) {
            float mo = __shfl_xor(pm[i], mk2);
            float d2 = __shfl_xor(pd[i], mk2);
            float n2 = __shfl_xor(pn[i], mk2);
            float M = fmaxf(pm[i], mo);
            float e1 = __expf(pm[i] - M), e2 = __expf(mo - M);
            pd[i] = pd[i] * e1 + d2 * e2;
            pn[i] = pn[i] * e1 + n2 * e2;
            pm[i] = M;
        }
    }
    if (tn == 0) {
#pragma unroll
        for (int i = 0; i < 4; ++i) {
            int b = tb * 4 + i;
            *(float4*)&p.partials[(size_t)(b * NTILES + tile) * 4] = make_float4(pm[i], pd[i], pn[i], 0.f);
        }
    }
}

__global__ __launch_bounds__(256, 2) void fused_kernel(KParams p) {
    cg::grid_group grid = cg::this_grid();
    __shared__ __align__(16) float sm[9280];
    int blk = blockIdx.x, tid = threadIdx.x;

    // ---------------- P0: zero mem + transposes + costab + wv_out/vconst/qconst + detect ----
    {
        int gtid = blk * 256 + tid;
        float4* m4 = (float4*)p.mem;
        float4 z4 = make_float4(0.f, 0.f, 0.f, 0.f);
        for (int i = gtid; i < (NN * LAT) / 4; i += NBLK * 256) m4[i] = z4;
        if (blk < 256) {
            const int GS = 256 * 256;
            for (int i = gtid; i < 129 * 384; i += GS) { int d = i / 384, j = i % 384; p.W_ihT[i] = p.W_ih[j * 129 + d]; }
            for (int i = gtid; i < 128 * 384; i += GS) { int l = i / 384, j = i % 384; p.W_hhT[i] = p.W_hh[j * 128 + l]; }
            for (int pp = gtid; pp <= KTAB; pp += GS) {
                float tv = (float)pp * (1.0f / KTAB);
                for (int l = 0; l < 128; ++l) p.costab[l * CSTRIDE + pp] = __cosf(tv * p.tw[l] + p.tb_[l]);
            }
        } else if (blk == 256) {
            for (int d = tid; d < DH; d += 256) {
                float a = 0.f;
                for (int j = 0; j < LAT; ++j) a += p.Wv[d * LAT + j] * p.W_out[j];
                p.wv_out[d] = a;
            }
            if (tid == 0) {
                float a = p.b_out[0];
                for (int j = 0; j < LAT; ++j) a += p.bv[j] * p.W_out[j];
                p.vconst[0] = a;
            }
            if (tid < 128) {
                float a = p.bq[tid];
                for (int j = 0; j < 128; ++j) a += __cosf(p.tb_[j]) * p.Wq[(129 + j) * LAT + tid];
                p.qconst[tid] = a;
            }
            int* smi = (int*)sm;
            if (tid == 0) { smi[0] = 0; smi[1] = 0; }
            __syncthreads();
            const int* mask = (const int*)p.maskp;
            for (int i = tid; i < 4096; i += 256) {
                int v = mask[i];
                if ((unsigned)v > 1u) atomicOr(&smi[0], 1);
                if (v == 0x3F800000) atomicOr(&smi[1], 1);
            }
            __syncthreads();
            if (tid == 0) p.modep[0] = smi[1] ? 2 : (smi[0] ? 1 : 0);
        }
    }
    grid.sync();

    // ---------------- P1: setup2 (131 units) + gtab (5 units) + GRU s=0 (128 units) ---------
    {
        if (blk < 131) {
            float* vrow = sm;   // 128
            if (blk < 128) {    // BT row l
                int l = blk;
                if (tid < 128) vrow[tid] = p.Wq[(1 + l) * LAT + tid];
                __syncthreads();
                for (int d = tid; d < DH; d += 256) {
                    const float* wkr = p.Wk + d * LAT;
                    float a = 0.f;
#pragma unroll 4
                    for (int j = 0; j < 128; ++j) a += wkr[j] * vrow[j];
                    p.BT[l * 260 + d] = a;
                }
            } else if (blk == 128) {    // uc = Wk @ qconst
                if (tid < 128) vrow[tid] = p.qconst[tid];
                __syncthreads();
                for (int d = tid; d < DH; d += 256) {
                    const float* wkr = p.Wk + d * LAT;
                    float a = 0.f;
#pragma unroll 4
                    for (int j = 0; j < 128; ++j) a += wkr[j] * vrow[j];
                    p.uc[d] = a;
                }
            } else if (blk == 129) {    // kw0 = Wk @ Wq[0,:]
                if (tid < 128) vrow[tid] = p.Wq[tid];
                __syncthreads();
                for (int d = tid; d < DH; d += 256) {
                    const float* wkr = p.Wk + d * LAT;
                    float a = 0.f;
#pragma unroll 4
                    for (int j = 0; j < 128; ++j) a += wkr[j] * vrow[j];
                    p.kw0[d] = a;
                }
            } else {                    // abk + scal
                if (tid < 128) vrow[tid] = p.bk[tid];
                __syncthreads();
                if (tid < 128) {
                    const float* wqr = p.Wq + (1 + tid) * LAT;
                    float a = 0.f;
#pragma unroll 4
                    for (int j = 0; j < 128; ++j) a += wqr[j] * vrow[j];
                    p.abk[tid] = a;
                } else if (tid == 128) {
                    float a = 0.f;
                    for (int j = 0; j < 128; ++j) a += p.qconst[j] * p.bk[j];
                    p.scal[0] = a;
                } else if (tid == 129) {
                    float a = 0.f;
                    for (int j = 0; j < 128; ++j) a += p.Wq[j] * p.bk[j];
                    p.scal[1] = a;
                }
            }
        } else if (blk < 136) {     // gtab
            float* wv_s = sm;
            if (tid < LAT) wv_s[tid] = p.wv_out[129 + tid];
            __syncthreads();
            int pp = (blk - 131) * 256 + tid;
            if (pp <= KTAB) {
                float a = 0.f;
                for (int l = 0; l < 128; ++l) a += wv_s[l] * p.costab[l * CSTRIDE + pp];
                p.gtab[pp] = a;
            }
        } else if (blk < 264) {     // GRU rows for s=0 (h = 0)
            do_gru_row256(blk - 136, tid, 0, 1, p.x, p.t, p.source, p.target, p.tw, p.tb_,
                          p.W_ihT, p.W_hhT, p.b_ih, p.b_hh, p.mem, p.newh, sm);
        }
    }
    grid.sync();

    // ---------------- main loop: A-phase | sync | B-phase | sync ----------------
    for (int s = 0; s < S_LEN; ++s) {
        if (blk < 64) {
            a_work256(p, sm, blk, s);
        } else if (blk == 64) {
            scatter256(p, sm, s);
        } else if (blk == 65) {
            if (s > 0) do_combine(p.partials, p.vconst, p.out, s - 1, tid);
        }
        grid.sync();
        if (blk < NTILES) {
            attn_tile256(p, sm, blk, s);
        } else {
            if (s < S_LEN - 1)
                do_gru_row256(blk - NTILES, tid, s + 1, 0, p.x, p.t, p.source, p.target,
                              p.tw, p.tb_, p.W_ihT, p.W_hhT, p.b_ih, p.b_hh, p.mem, p.newh, sm);
        }
        grid.sync();
    }
    if (blk == 0) do_combine(p.partials, p.vconst, p.out, S_LEN - 1, tid);
}

// ============================================================================================
// Fallback path: the previous verified multi-kernel implementation (used only if the
// cooperative launch is rejected by the runtime).
// ============================================================================================
__global__ __launch_bounds__(256) void setup_all_kernel(
    const float* __restrict__ W_ih, const float* __restrict__ W_hh,
    const float* __restrict__ tw, const float* __restrict__ tb_,
    const float* __restrict__ Wq, const float* __restrict__ bq,
    const float* __restrict__ Wv, const float* __restrict__ bv,
    const float* __restrict__ W_out, const float* __restrict__ b_out,
    const int* __restrict__ mask,
    float* __restrict__ W_ihT, float* __restrict__ W_hhT,
    float* __restrict__ costab, float* __restrict__ wv_out, float* __restrict__ vconst,
    float* __restrict__ qconst, int* __restrict__ modep) {
    int blk = blockIdx.x, tid = threadIdx.x;
    if (blk < 256) {
        int gtid = blk * 256 + tid;
        const int GS = 256 * 256;
        for (int i = gtid; i < 129 * 384; i += GS) { int d = i / 384, j = i % 384; W_ihT[i] = W_ih[j * 129 + d]; }
        for (int i = gtid; i < 128 * 384; i += GS) { int l = i / 384, j = i % 384; W_hhT[i] = W_hh[j * 128 + l]; }
        for (int p = gtid; p <= KTAB; p += GS) {
            float tv = (float)p * (1.0f / KTAB);
            for (int l = 0; l < 128; ++l) costab[l * CSTRIDE + p] = __cosf(tv * tw[l] + tb_[l]);
        }
    } else {
        for (int d = tid; d < DH; d += 256) {
            float a = 0.f;
            for (int j = 0; j < LAT; ++j) a += Wv[d * LAT + j] * W_out[j];
            wv_out[d] = a;
        }
        if (tid == 0) {
            float a = b_out[0];
            for (int j = 0; j < LAT; ++j) a += bv[j] * W_out[j];
            *vconst = a;
        }
        if (tid < 128) {
            float a = bq[tid];
            for (int j = 0; j < 128; ++j) a += __cosf(tb_[j]) * Wq[(129 + j) * LAT + tid];
            qconst[tid] = a;
        }
        __shared__ int hasHigh, hasFloat;
        if (tid == 0) { hasHigh = 0; hasFloat = 0; }
        __syncthreads();
        for (int i = tid; i < 4096; i += 256) {
            int v = mask[i];
            if ((unsigned)v > 1u) atomicOr(&hasHigh, 1);
            if (v == 0x3F800000) atomicOr(&hasFloat, 1);
        }
        __syncthreads();
        if (tid == 0) *modep = hasFloat ? 2 : (hasHigh ? 1 : 0);
    }
}

__global__ __launch_bounds__(256) void setup2_kernel(
    const float* __restrict__ Wk, const float* __restrict__ Wq,
    const float* __restrict__ bk, const float* __restrict__ qconst,
    float* __restrict__ BT, float* __restrict__ uc, float* __restrict__ kw0,
    float* __restrict__ abk, float* __restrict__ scal) {
    int blk = blockIdx.x, tid = threadIdx.x;
    __shared__ float vrow[128];
    if (blk < 128) {
        int l = blk;
        if (tid < 128) vrow[tid] = Wq[(1 + l) * LAT + tid];
        __syncthreads();
        for (int d = tid; d < DH; d += 256) {
            const float* wkr = Wk + d * LAT;
            float a = 0.f;
#pragma unroll 4
            for (int j = 0; j < 128; ++j) a += wkr[j] * vrow[j];
            BT[l * 260 + d] = a;
        }
    } else if (blk == 128) {
        if (tid < 128) vrow[tid] = qconst[tid];
        __syncthreads();
        for (int d = tid; d < DH; d += 256) {
            const float* wkr = Wk + d * LAT;
            float a = 0.f;
#pragma unroll 4
            for (int j = 0; j < 128; ++j) a += wkr[j] * vrow[j];
            uc[d] = a;
        }
    } else if (blk == 129) {
        if (tid < 128) vrow[tid] = Wq[tid];
        __syncthreads();
        for (int d = tid; d < DH; d += 256) {
            const float* wkr = Wk + d * LAT;
            float a = 0.f;
#pragma unroll 4
            for (int j = 0; j < 128; ++j) a += wkr[j] * vrow[j];
            kw0[d] = a;
        }
    } else {
        if (tid < 128) vrow[tid] = bk[tid];
        __syncthreads();
        if (tid < 128) {
            const float* wqr = Wq + (1 + tid) * LAT;
            float a = 0.f;
#pragma unroll 4
            for (int j = 0; j < 128; ++j) a += wqr[j] * vrow[j];
            abk[tid] = a;
        } else if (tid == 128) {
            float a = 0.f;
            for (int j = 0; j < 128; ++j) a += qconst[j] * bk[j];
            scal[0] = a;
        } else if (tid == 129) {
            float a = 0.f;
            for (int j = 0; j < 128; ++j) a += Wq[j] * bk[j];
            scal[1] = a;
        }
    }
}

__global__ __launch_bounds__(256) void pre_kernel(
    const float* __restrict__ x, const float* __restrict__ t,
    const int* __restrict__ source, const int* __restrict__ target,
    const float* __restrict__ tw, const float* __restrict__ tb_,
    const float* __restrict__ W_ihT, const float* __restrict__ W_hhT,
    const float* __restrict__ b_ih, const float* __restrict__ b_hh,
    const float* __restrict__ mem, float* __restrict__ newh,
    const float* __restrict__ wv_out, const float* __restrict__ costab,
    float* __restrict__ gtab) {
    __shared__ __align__(16) float sm[1028];
    int blk = blockIdx.x, tid = threadIdx.x;
    if (blk < 5) {
        __shared__ float wv_s[LAT];
        if (tid < LAT) wv_s[tid] = wv_out[129 + tid];
        __syncthreads();
        int p = blk * 256 + tid;
        if (p <= KTAB) {
            float a = 0.f;
            for (int l = 0; l < 128; ++l) a += wv_s[l] * costab[l * CSTRIDE + p];
            gtab[p] = a;
        }
        return;
    }
    int r = blk - 5;
    do_gru_row256(r, tid, 0, 0, x, t, source, target, tw, tb_,
                  W_ihT, W_hhT, b_ih, b_hh, mem, newh, sm);
}

__global__ __launch_bounds__(512) void step_a3_kernel(
    const float* __restrict__ x, const int* __restrict__ source, const int* __restrict__ target,
    const float* __restrict__ BT, const float* __restrict__ uc, const float* __restrict__ kw0,
    const float* __restrict__ abk, const float* __restrict__ scal,
    const float* __restrict__ newh, float* __restrict__ mem,
    float* __restrict__ u0_g, float* __restrict__ qbk_g, float* __restrict__ uT,
    float* __restrict__ ftab, const float* __restrict__ costab,
    const float* __restrict__ partials, const float* __restrict__ vconst,
    float* __restrict__ out, int s) {
    int blk = blockIdx.x;
    int tid = threadIdx.x;
    if (blk == 64) {
        __shared__ int idxs[128];
        __shared__ int alive[128];
        if (tid < 128) idxs[tid] = (tid < 64) ? source[s * BSZ + tid] : target[s * BSZ + (tid - 64)];
        __syncthreads();
        if (tid < 128) {
            int i2 = idxs[tid];
            int a = 1;
            for (int r2 = tid + 1; r2 < 128; ++r2)
                if (idxs[r2] == i2) { a = 0; break; }
            alive[tid] = a;
        }
        __syncthreads();
        int row = tid >> 2, q4 = tid & 3;
        if (alive[row]) {
            const float4* srcp = (const float4*)(newh + row * LAT + q4 * 32);
            float4* dstp = (float4*)(mem + (size_t)idxs[row] * LAT + q4 * 32);
#pragma unroll
            for (int j = 0; j < 8; ++j) dstp[j] = srcp[j];
        }
        return;
    }
    if (blk == 65) {
        if (s > 0) do_combine(partials, vconst, out, s - 1, tid);
        return;
    }
    int b = blk;
    __shared__ float memv[128];
    __shared__ float udt_s[128];
    __shared__ float upart[4][260];
    __shared__ float red[8];
    __shared__ __align__(16) float fpart[3 * 1024];
    __shared__ int s_last;
    __shared__ float xvs;
    if (tid < 64) {
        unsigned long long mball = __ballot(target[s * BSZ + tid] == target[s * BSZ + b]);
        if (tid == 0) {
            s_last = 63 - __builtin_clzll(mball);
            xvs = x[(size_t)(s * BSZ + b) * NN + target[s * BSZ + b]];
        }
    }
    __syncthreads();
    if (tid < 128) memv[tid] = newh[(64 + s_last) * LAT + tid];
    __syncthreads();
    float xv = xvs;
    {
        int dd = tid & 127, kc = tid >> 7;
        int l0 = kc * 32;
        for (int d = dd; d < DH; d += 128) {
            float a = 0.f;
#pragma unroll 4
            for (int l = l0; l < l0 + 32; ++l) a += memv[l] * BT[l * 260 + d];
            upart[kc][d] = a;
        }
    }
    __syncthreads();
    if (tid < 257) {
        float a = uc[tid] + xv * kw0[tid] + upart[0][tid] + upart[1][tid] + upart[2][tid] + upart[3][tid];
        if (tid == 0) u0_g[b] = a;
        else if (tid <= 128) uT[(tid - 1) * BSZ + b] = a;
        else udt_s[tid - 129] = a;
    }
    if (tid >= 448) {
        int i = tid - 448;
        float a = memv[i] * abk[i] + memv[64 + i] * abk[64 + i];
        for (int off = 32; off; off >>= 1) a += __shfl_down(a, off, 64);
        if (i == 0) qbk_g[b] = scal[0] + xv * scal[1] + a;
    }
    __syncthreads();
    {
        int pi = tid & 127, lc = tid >> 7;
        int l0 = lc * 32;
        float a0x = 0.f, a0y = 0.f, a0z = 0.f, a0w = 0.f;
        float a1x = 0.f, a1y = 0.f, a1z = 0.f, a1w = 0.f;
#pragma unroll 4
        for (int l = l0; l < l0 + 32; ++l) {
            float ul = udt_s[l];
            const float* cp = &costab[l * CSTRIDE + pi * 8];
            float4 c0 = *(const float4*)cp;
            float4 c1 = *(const float4*)(cp + 4);
            a0x += ul * c0.x; a0y += ul * c0.y; a0z += ul * c0.z; a0w += ul * c0.w;
            a1x += ul * c1.x; a1y += ul * c1.y; a1z += ul * c1.z; a1w += ul * c1.w;
        }
        if (lc) {
            float* fp = &fpart[(lc - 1) * 1024 + pi * 8];
            *(float4*)fp = make_float4(a0x, a0y, a0z, a0w);
            *(float4*)(fp + 4) = make_float4(a1x, a1y, a1z, a1w);
        }
        if (pi == 127) {
            float a = 0.f;
            for (int l = l0; l < l0 + 32; ++l) a += udt_s[l] * costab[l * CSTRIDE + KTAB];
            red[lc] = a;
        }
        __syncthreads();
        if (lc == 0) {
            for (int c = 0; c < 3; ++c) {
                const float* fp = &fpart[c * 1024 + pi * 8];
                a0x += fp[0]; a0y += fp[1]; a0z += fp[2]; a0w += fp[3];
                a1x += fp[4]; a1y += fp[5]; a1z += fp[6]; a1w += fp[7];
            }
            float* fo = &ftab[b * FSTRIDE + pi * 8];
            *(float4*)fo = make_float4(a0x, a0y, a0z, a0w);
            *(float4*)(fo + 4) = make_float4(a1x, a1y, a1z, a1w);
        }
        if (tid == 0) ftab[b * FSTRIDE + KTAB] = red[0] + red[1] + red[2] + red[3];
    }
}

__global__ __launch_bounds__(256) void step_b2_kernel(
    const float* __restrict__ x, const float* __restrict__ t,
    const void* __restrict__ maskp, const int* __restrict__ modep,
    const int* __restrict__ source, const int* __restrict__ target,
    const float* __restrict__ tw, const float* __restrict__ tb_,
    const float* __restrict__ W_ihT, const float* __restrict__ W_hhT,
    const float* __restrict__ b_ih, const float* __restrict__ b_hh,
    const float* __restrict__ mem, float* __restrict__ newh,
    const float* __restrict__ uT, const float* __restrict__ u0_g,
    const float* __restrict__ qbk_g, const float* __restrict__ ftab,
    const float* __restrict__ gtab, const float* __restrict__ wv_out,
    float* __restrict__ partials, int s) {
    int blk = blockIdx.x, tid = threadIdx.x;
    __shared__ __align__(16) float sm[9280];
    if (blk >= NTILES) {
        if (s < S_LEN - 1) {
            int r = blk - NTILES;
            do_gru_row256(r, tid, s + 1, 0, x, t, source, target, tw, tb_,
                          W_ihT, W_hhT, b_ih, b_hh, mem, newh, sm);
        }
        return;
    }
    KParams p;
    p.x = x; p.t = t; p.maskp = maskp; p.modep = (int*)modep;
    p.mem = (float*)mem; p.uT = (float*)uT; p.u0_g = (float*)u0_g; p.qbk_g = (float*)qbk_g;
    p.ftab = (float*)ftab; p.gtab = (float*)gtab; p.wv_out = (float*)wv_out;
    p.partials = (float*)partials;
    attn_tile256(p, sm, blk, s);
}

__global__ __launch_bounds__(64) void tail_kernel(const float* __restrict__ partials,
                                                  const float* __restrict__ vconst,
                                                  float* __restrict__ out) {
    do_combine(partials, vconst, out, S_LEN - 1, threadIdx.x);
}

extern "C" void kernel_launch(void* const* d_in, const int* in_sizes, int n_in,
                              void* d_out, int out_size, void* d_ws, size_t ws_size,
                              hipStream_t stream) {
    const float* x      = (const float*)d_in[0];
    const float* t      = (const float*)d_in[1];
    const int*   source = (const int*)d_in[2];
    const int*   target = (const int*)d_in[3];
    const void*  maskp  = (const void*)d_in[4];
    const float* tw     = (const float*)d_in[5];
    const float* tb     = (const float*)d_in[6];
    const float* W_ih   = (const float*)d_in[7];
    const float* W_hh   = (const float*)d_in[8];
    const float* b_ih   = (const float*)d_in[9];
    const float* b_hh   = (const float*)d_in[10];
    const float* Wq     = (const float*)d_in[11];
    const float* bq     = (const float*)d_in[12];
    const float* Wk     = (const float*)d_in[13];
    const float* bk     = (const float*)d_in[14];
    const float* Wv     = (const float*)d_in[15];
    const float* bv     = (const float*)d_in[16];
    const float* W_out  = (const float*)d_in[17];
    const float* b_out  = (const float*)d_in[18];
    float* out = (float*)d_out;

    float* w = (float*)d_ws;
    float* mem    = w; w += (size_t)NN * LAT;
    float* newh   = w; w += 128 * LAT;
    float* uT     = w; w += LAT * BSZ;
    float* u0_g   = w; w += BSZ;
    float* qbk_g  = w; w += BSZ;
    float* ftab   = w; w += BSZ * FSTRIDE;
    float* gtab   = w; w += FSTRIDE;
    float* costab = w; w += LAT * CSTRIDE;
    float* partials = w; w += (size_t)BSZ * NTILES * 4;
    float* wv_out = w; w += 260;
    float* vconst = w; w += 4;
    float* W_ihT  = w; w += 129 * 384;
    float* W_hhT  = w; w += 128 * 384;
    float* BT     = w; w += 128 * 260;
    float* uc     = w; w += 260;
    float* kw0    = w; w += 260;
    float* abk    = w; w += 128;
    float* qconst = w; w += 128;
    float* scal   = w; w += 8;
    int*   modep  = (int*)w;

    KParams kp;
    kp.x = x; kp.t = t; kp.source = source; kp.target = target; kp.maskp = maskp;
    kp.tw = tw; kp.tb_ = tb;
    kp.W_ih = W_ih; kp.W_hh = W_hh; kp.b_ih = b_ih; kp.b_hh = b_hh;
    kp.Wq = Wq; kp.bq = bq; kp.Wk = Wk; kp.bk = bk; kp.Wv = Wv; kp.bv = bv;
    kp.W_out = W_out; kp.b_out = b_out;
    kp.out = out;
    kp.mem = mem; kp.newh = newh; kp.uT = uT; kp.u0_g = u0_g; kp.qbk_g = qbk_g;
    kp.ftab = ftab; kp.gtab = gtab; kp.costab = costab; kp.partials = partials;
    kp.wv_out = wv_out; kp.vconst = vconst; kp.W_ihT = W_ihT; kp.W_hhT = W_hhT;
    kp.BT = BT; kp.uc = uc; kp.kw0 = kw0; kp.abk = abk; kp.qconst = qconst; kp.scal = scal;
    kp.modep = modep;

    void* args[] = { &kp };
    hipError_t err = hipLaunchCooperativeKernel((const void*)fused_kernel,
                                                dim3(NBLK), dim3(256), args, 0, stream);
    if (err != hipSuccess) {
        // Fallback: previous verified multi-kernel path.
        hipMemsetAsync(mem, 0, (size_t)NN * LAT * sizeof(float), stream);
        setup_all_kernel<<<257, 256, 0, stream>>>(W_ih, W_hh, tw, tb, Wq, bq, Wv, bv, W_out, b_out,
                                                  (const int*)maskp, W_ihT, W_hhT,
                                                  costab, wv_out, vconst, qconst, modep);
        setup2_kernel<<<131, 256, 0, stream>>>(Wk, Wq, bk, qconst, BT, uc, kw0, abk, scal);
        pre_kernel<<<133, 256, 0, stream>>>(x, t, source, target, tw, tb,
                                            W_ihT, W_hhT, b_ih, b_hh, mem, newh,
                                            wv_out, costab, gtab);
        for (int s = 0; s < S_LEN; ++s) {
            step_a3_kernel<<<66, 512, 0, stream>>>(x, source, target, BT, uc, kw0, abk, scal,
                                                   newh, mem, u0_g, qbk_g, uT, ftab, costab,
                                                   partials, vconst, out, s);
            step_b2_kernel<<<NTILES + 128, 256, 0, stream>>>(x, t, maskp, modep, source, target,
                                                             tw, tb, W_ihT, W_hhT, b_ih, b_hh,
                                                             mem, newh, uT, u0_g, qbk_g,
                                                             ftab, gtab, wv_out, partials, s);
        }
        tail_kernel<<<1, 64, 0, stream>>>(partials, vconst, out);
    }
}

// Round 2
// 2375.706 us; speedup vs baseline: 1.1280x; 1.1280x over previous
//
#include <hip/hip_runtime.h>
#include <math.h>

#define S_LEN 16
#define BSZ   64
#define NN    10000
#define LAT   128
#define DH    257
#define KTAB  1024
#define CSTRIDE (KTAB + 8)    // costab leading dim
#define FSTRIDE (KTAB + 4)    // ftab leading dim
#define NTILE 64
#define NTILES 157            // ceil(10000/64)
#define NBLK  (NTILES + 128)  // 285 fused grid
#define SCALE 0.08838834764831845f
#define NEG1E9 -1000000000.0f

// ---- lightweight grid barrier: monotonic counter, agent-scope atomics, relaxed-load spin ----
__device__ __forceinline__ void gbar(unsigned* cnt, unsigned target) {
    __syncthreads();
    asm volatile("" ::: "memory");
    if (threadIdx.x == 0) {
        __threadfence();   // agent release: drain + L2 writeback
        __hip_atomic_fetch_add(cnt, 1u, __ATOMIC_RELAXED, __HIP_MEMORY_SCOPE_AGENT);
        while (__hip_atomic_load(cnt, __ATOMIC_RELAXED, __HIP_MEMORY_SCOPE_AGENT) < target)
            __builtin_amdgcn_s_sleep(2);
        __threadfence();   // agent acquire: L1/L2 invalidate
    }
    asm volatile("" ::: "memory");
    __syncthreads();
}

// ================= GRU one row with 256 threads, uses caller's 1028-float sm =================
__device__ __forceinline__ void do_gru_row256(int r, int tid2, int s, int zeroH,
    const float* __restrict__ x, const float* __restrict__ t,
    const int* __restrict__ source, const int* __restrict__ target,
    const float* __restrict__ tw, const float* __restrict__ tb_,
    const float* __restrict__ W_ihT, const float* __restrict__ W_hhT,
    const float* __restrict__ b_ih, const float* __restrict__ b_hh,
    const float* __restrict__ mem, float* __restrict__ newh, float* sm) {
    float* msg = sm;          // 132
    float* h   = sm + 132;    // 128
    float* gi3 = sm + 260;    // 384
    float* gh3 = sm + 644;    // 384
    int b = r & 63;
    int idx = (r < 64) ? source[s * BSZ + b] : target[s * BSZ + b];
    const float* xs = x + (size_t)(s * BSZ + b) * NN;
    const float* ts = t + (size_t)(s * BSZ + b) * NN;
    if (tid2 == 0) msg[0] = xs[idx];
    if (tid2 < 128) {
        float tv = ts[idx];
        msg[1 + tid2] = __cosf(tv * tw[tid2] + tb_[tid2]);
        h[tid2] = zeroH ? 0.f : mem[(size_t)idx * LAT + tid2];
    }
    __syncthreads();
    if (tid2 < 128) {
        int j = tid2;
        float a0 = b_ih[j], a1 = b_ih[128 + j], a2 = b_ih[256 + j];
#pragma unroll 4
        for (int d = 0; d < 129; ++d) {
            float m = msg[d];
            const float* col = W_ihT + d * 384;
            a0 += m * col[j]; a1 += m * col[128 + j]; a2 += m * col[256 + j];
        }
        gi3[j] = a0; gi3[128 + j] = a1; gi3[256 + j] = a2;
    } else {
        int j = tid2 - 128;
        float a0 = b_hh[j], a1 = b_hh[128 + j], a2 = b_hh[256 + j];
#pragma unroll 4
        for (int l = 0; l < 128; ++l) {
            float hv = h[l];
            const float* col = W_hhT + l * 384;
            a0 += hv * col[j]; a1 += hv * col[128 + j]; a2 += hv * col[256 + j];
        }
        gh3[j] = a0; gh3[128 + j] = a1; gh3[256 + j] = a2;
    }
    __syncthreads();
    if (tid2 < 128) {
        int j = tid2;
        float rr = 1.f / (1.f + __expf(-(gi3[j] + gh3[j])));
        float zz = 1.f / (1.f + __expf(-(gi3[128 + j] + gh3[128 + j])));
        float nn2 = tanhf(gi3[256 + j] + rr * gh3[256 + j]);
        newh[r * LAT + j] = (1.f - zz) * nn2 + zz * h[j];
    }
}

// ================= combine partials -> logit (tid<64) =================
__device__ __forceinline__ void do_combine(const float* __restrict__ partials,
                                           const float* __restrict__ vconst,
                                           float* __restrict__ out, int ps, int tid) {
    if (tid >= 64) return;
    int b = tid;
    float M = -3.0e38f, D = 0.f, Nm = 0.f;
    const float4* pp = (const float4*)partials + b * NTILES;
    for (int i = 0; i < NTILES; ++i) {
        float4 p = pp[i];
        float M2 = fmaxf(M, p.x);
        float e1 = __expf(M - M2), e2 = __expf(p.x - M2);
        D = D * e1 + p.y * e2;
        Nm = Nm * e1 + p.z * e2;
        M = M2;
    }
    out[ps * BSZ + b] = Nm / D + vconst[0];
}

// ============================================================================================
// Fused persistent cooperative kernel: setup + pre + 16x(A,B) + tail in ONE dispatch.
// ============================================================================================
struct KParams {
    const float *x, *t;
    const int *source, *target;
    const void *maskp;
    const float *tw, *tb_;
    const float *W_ih, *W_hh, *b_ih, *b_hh;
    const float *Wq, *bq, *Wk, *bk, *Wv, *bv, *W_out, *b_out;
    float *out;
    float *mem, *newh, *uT, *u0_g, *qbk_g, *ftab, *gtab, *costab, *partials;
    float *wv_out, *vconst, *W_ihT, *W_hhT, *BT, *uc, *kw0, *abk, *qconst, *scal;
    int *modep;
    unsigned *barcnt;
};

// ---- A-phase per-b work, 256 threads ----
__device__ void a_work256(const KParams& p, float* sm, int b, int s) {
    float* memv  = sm;            // 128
    float* udt_s = sm + 128;      // 128
    float* upart = sm + 256;      // 2*260 = 520
    float* red   = sm + 776;      // 2 (room to 784)
    float* fpart = sm + 784;      // 1024 -> ends 1808
    float* xvs_p = sm + 1808;
    int*   slast_p = (int*)(sm + 1809);
    int tid = threadIdx.x;

    if (tid < 64) {
        unsigned long long mball = __ballot(p.target[s * BSZ + tid] == p.target[s * BSZ + b]);
        if (tid == 0) {
            *slast_p = 63 - __builtin_clzll(mball);
            *xvs_p = p.x[(size_t)(s * BSZ + b) * NN + p.target[s * BSZ + b]];
        }
    }
    __syncthreads();
    int s_last = *slast_p;
    if (tid < 128) memv[tid] = p.newh[(64 + s_last) * LAT + tid];   // post-scatter mem[tg]
    __syncthreads();
    float xv = *xvs_p;
    {   // u[d] = uc[d] + xv*kw0[d] + sum_l memv[l]*BT[l*260+d], K split 2 ways (chain 64)
        int dd = tid & 127, kc = tid >> 7;
        int l0 = kc * 64;
        for (int d = dd; d < DH; d += 128) {
            float a = 0.f;
#pragma unroll 4
            for (int l = l0; l < l0 + 64; ++l) a += memv[l] * p.BT[l * 260 + d];
            upart[kc * 260 + d] = a;
        }
    }
    __syncthreads();
    {
        float a = p.uc[tid] + xv * p.kw0[tid] + upart[tid] + upart[260 + tid];
        if (tid == 0) p.u0_g[b] = a;
        else if (tid <= 128) p.uT[(tid - 1) * BSZ + b] = a;
        else udt_s[tid - 129] = a;                 // d = 129..255 -> udt_s[0..126]
        if (tid == 0) {                            // d = 256 -> udt_s[127]
            float a2 = p.uc[256] + xv * p.kw0[256] + upart[256] + upart[516];
            udt_s[127] = a2;
        }
    }
    if (tid >= 192) {   // qbk = scal0 + xv*scal1 + memv.abk  (one wave: wave 3)
        int i = tid - 192;
        float a = memv[i] * p.abk[i] + memv[64 + i] * p.abk[64 + i];
        for (int off = 32; off; off >>= 1) a += __shfl_down(a, off, 64);
        if (i == 0) p.qbk_g[b] = p.scal[0] + xv * p.scal[1] + a;
    }
    __syncthreads();
    {   // ftab: 8 points/thread, L split 2 ways (chain 64)
        int pi = tid & 127, lc = tid >> 7;
        int l0 = lc * 64;
        float a0x = 0.f, a0y = 0.f, a0z = 0.f, a0w = 0.f;
        float a1x = 0.f, a1y = 0.f, a1z = 0.f, a1w = 0.f;
#pragma unroll 4
        for (int l = l0; l < l0 + 64; ++l) {
            float ul = udt_s[l];
            const float* cp = &p.costab[l * CSTRIDE + pi * 8];
            float4 c0 = *(const float4*)cp;
            float4 c1 = *(const float4*)(cp + 4);
            a0x += ul * c0.x; a0y += ul * c0.y; a0z += ul * c0.z; a0w += ul * c0.w;
            a1x += ul * c1.x; a1y += ul * c1.y; a1z += ul * c1.z; a1w += ul * c1.w;
        }
        if (lc) {
            float* fp = &fpart[pi * 8];
            *(float4*)fp = make_float4(a0x, a0y, a0z, a0w);
            *(float4*)(fp + 4) = make_float4(a1x, a1y, a1z, a1w);
        }
        if (pi == 127) {
            float a = 0.f;
            for (int l = l0; l < l0 + 64; ++l) a += udt_s[l] * p.costab[l * CSTRIDE + KTAB];
            red[lc] = a;
        }
        __syncthreads();
        if (lc == 0) {
            const float* fp = &fpart[pi * 8];
            a0x += fp[0]; a0y += fp[1]; a0z += fp[2]; a0w += fp[3];
            a1x += fp[4]; a1y += fp[5]; a1z += fp[6]; a1w += fp[7];
            float* fo = &p.ftab[b * FSTRIDE + pi * 8];
            *(float4*)fo = make_float4(a0x, a0y, a0z, a0w);
            *(float4*)(fo + 4) = make_float4(a1x, a1y, a1z, a1w);
        }
        if (tid == 0) p.ftab[b * FSTRIDE + KTAB] = red[0] + red[1];
    }
}

// ---- scatter, 256 threads (2 threads/row) ----
__device__ void scatter256(const KParams& p, float* sm, int s) {
    int* idxs  = (int*)sm;
    int* alive = idxs + 128;
    int tid = threadIdx.x;
    if (tid < 128) idxs[tid] = (tid < 64) ? p.source[s * BSZ + tid] : p.target[s * BSZ + (tid - 64)];
    __syncthreads();
    if (tid < 128) {
        int i2 = idxs[tid];
        int a = 1;
        for (int r2 = tid + 1; r2 < 128; ++r2)
            if (idxs[r2] == i2) { a = 0; break; }
        alive[tid] = a;
    }
    __syncthreads();
    int row = tid >> 1, q2 = tid & 1;
    if (alive[row]) {
        const float4* srcp = (const float4*)(p.newh + row * LAT + q2 * 64);
        float4* dstp = (float4*)(p.mem + (size_t)idxs[row] * LAT + q2 * 64);
#pragma unroll
        for (int j = 0; j < 16; ++j) dstp[j] = srcp[j];
    }
}

// ---- attention tile, 256 threads ----
__device__ void attn_tile256(const KParams& p, float* sm, int tile, int s) {
    float* memT   = sm;           // 64*72 = 4608
    float* uTs    = sm + 4608;    // 64*68 = 4352
    float* memv_s = sm + 8960;    // 64
    float* wv_s   = sm + 9024;    // 128
    float* u0_s   = sm + 9152;    // 64
    float* qbk_s  = sm + 9216;    // 64  (total 9280)
    int tid = threadIdx.x;
    int n0 = tile * NTILE;
    int tb = tid >> 4, tn = tid & 15;
    int nvalid = NN - n0; if (nvalid > NTILE) nvalid = NTILE;

    if (tid < 128) wv_s[tid] = p.wv_out[1 + tid];
    if (tid < 64) { u0_s[tid] = p.u0_g[tid]; qbk_s[tid] = p.qbk_g[tid]; memv_s[tid] = 0.f; }

    float acc[4][4];
#pragma unroll
    for (int i = 0; i < 4; ++i)
#pragma unroll
        for (int j = 0; j < 4; ++j) acc[i][j] = 0.f;

    for (int l0 = 0; l0 < 128; l0 += 64) {
        __syncthreads();
        {   // stage mem -> memT transposed
            int n_l = tid & 63, lq = (tid >> 6) * 16;
            if (n_l < nvalid) {
                const float* mrow = p.mem + (size_t)(n0 + n_l) * LAT + l0 + lq;
                float4 a0 = *(const float4*)(mrow + 0);
                float4 a1 = *(const float4*)(mrow + 4);
                float4 a2 = *(const float4*)(mrow + 8);
                float4 a3 = *(const float4*)(mrow + 12);
                memT[(lq + 0) * 72 + n_l] = a0.x; memT[(lq + 1) * 72 + n_l] = a0.y;
                memT[(lq + 2) * 72 + n_l] = a0.z; memT[(lq + 3) * 72 + n_l] = a0.w;
                memT[(lq + 4) * 72 + n_l] = a1.x; memT[(lq + 5) * 72 + n_l] = a1.y;
                memT[(lq + 6) * 72 + n_l] = a1.z; memT[(lq + 7) * 72 + n_l] = a1.w;
                memT[(lq + 8) * 72 + n_l] = a2.x; memT[(lq + 9) * 72 + n_l] = a2.y;
                memT[(lq + 10) * 72 + n_l] = a2.z; memT[(lq + 11) * 72 + n_l] = a2.w;
                memT[(lq + 12) * 72 + n_l] = a3.x; memT[(lq + 13) * 72 + n_l] = a3.y;
                memT[(lq + 14) * 72 + n_l] = a3.z; memT[(lq + 15) * 72 + n_l] = a3.w;
            } else {
                for (int j = 0; j < 16; ++j) memT[(lq + j) * 72 + n_l] = 0.f;
            }
        }
        {   // stage uT chunk -> uTs
            int bq4 = (tid & 15) * 4;
            int ll = (tid >> 4) * 4;
            for (int j = 0; j < 4; ++j) {
                float4 v = *(const float4*)&p.uT[(l0 + ll + j) * BSZ + bq4];
                *(float4*)&uTs[(ll + j) * 68 + bq4] = v;
            }
        }
        __syncthreads();
        if (tid < 64) {   // memv partial
            float a = memv_s[tid];
            for (int l = 0; l < 64; ++l) a += wv_s[l0 + l] * memT[l * 72 + tid];
            memv_s[tid] = a;
        }
        for (int l = 0; l < 64; ++l) {
            float4 uv = *(const float4*)&uTs[l * 68 + tb * 4];
            float4 mv = *(const float4*)&memT[l * 72 + tn * 4];
            acc[0][0] += uv.x * mv.x; acc[0][1] += uv.x * mv.y; acc[0][2] += uv.x * mv.z; acc[0][3] += uv.x * mv.w;
            acc[1][0] += uv.y * mv.x; acc[1][1] += uv.y * mv.y; acc[1][2] += uv.y * mv.z; acc[1][3] += uv.y * mv.w;
            acc[2][0] += uv.z * mv.x; acc[2][1] += uv.z * mv.y; acc[2][2] += uv.z * mv.z; acc[2][3] += uv.z * mv.w;
            acc[3][0] += uv.w * mv.x; acc[3][1] += uv.w * mv.y; acc[3][2] += uv.w * mv.z; acc[3][3] += uv.w * mv.w;
        }
    }
    __syncthreads();

    const float c0 = p.wv_out[0];
    int mode = p.modep[0];
    const int* m32 = (const int*)p.maskp;
    const unsigned char* m8 = (const unsigned char*)p.maskp;
    const float* mf = (const float*)p.maskp;

    float pm[4], pd[4], pn[4];
#pragma unroll
    for (int i = 0; i < 4; ++i) { pm[i] = -3.0e38f; pd[i] = 0.f; pn[i] = 0.f; }

    for (int i = 0; i < 4; ++i) {
        int b = tb * 4 + i;
        size_t base = (size_t)(s * BSZ + b) * NN + n0 + tn * 4;
        float xv4[4], tv4[4]; int msk[4], vld[4];
        if (tn * 4 + 3 < nvalid) {
            float4 xx = *(const float4*)(p.x + base);
            float4 tt = *(const float4*)(p.t + base);
            xv4[0] = xx.x; xv4[1] = xx.y; xv4[2] = xx.z; xv4[3] = xx.w;
            tv4[0] = tt.x; tv4[1] = tt.y; tv4[2] = tt.z; tv4[3] = tt.w;
            if (mode == 1) {
                unsigned mw = *(const unsigned*)(m8 + base);
                msk[0] = mw & 0xff; msk[1] = (mw >> 8) & 0xff; msk[2] = (mw >> 16) & 0xff; msk[3] = (mw >> 24) & 0xff;
            } else if (mode == 2) {
                float4 mm = *(const float4*)(mf + base);
                msk[0] = (mm.x != 0.f); msk[1] = (mm.y != 0.f); msk[2] = (mm.z != 0.f); msk[3] = (mm.w != 0.f);
            } else {
                int4 mm = *(const int4*)(m32 + base);
                msk[0] = mm.x; msk[1] = mm.y; msk[2] = mm.z; msk[3] = mm.w;
            }
            vld[0] = vld[1] = vld[2] = vld[3] = 1;
        } else {
            for (int j = 0; j < 4; ++j) {
                int n = tn * 4 + j;
                vld[j] = (n < nvalid);
                if (vld[j]) {
                    xv4[j] = p.x[base + j]; tv4[j] = p.t[base + j];
                    msk[j] = (mode == 1) ? (int)m8[base + j] : (mode == 2) ? (mf[base + j] != 0.f) : m32[base + j];
                } else { xv4[j] = 0.f; tv4[j] = 0.f; msk[j] = 0; }
            }
        }
        const float* ft = p.ftab + b * FSTRIDE;
#pragma unroll
        for (int j = 0; j < 4; ++j) {
            if (!vld[j]) continue;
            float xv = xv4[j], tv = tv4[j];
            float pq = tv * (float)KTAB;
            pq = fminf(fmaxf(pq, 0.f), (float)KTAB - 0.001f);
            int ii = (int)pq;
            float fr = pq - (float)ii;
            float f0 = ft[ii];
            float fv = f0 + (ft[ii + 1] - f0) * fr;
            float g0 = p.gtab[ii];
            float gv = g0 + (p.gtab[ii + 1] - g0) * fr;
            float sc = SCALE * (xv * u0_s[b] + acc[i][j] + fv + qbk_s[b]);
            if (msk[j] == 0) sc = NEG1E9;
            float val = xv * c0 + memv_s[tn * 4 + j] + gv;
            if (sc > pm[i]) {
                float a = __expf(pm[i] - sc);
                pd[i] = pd[i] * a + 1.f;
                pn[i] = pn[i] * a + val;
                pm[i] = sc;
            } else {
                float e = __expf(sc - pm[i]);
                pd[i] += e;
                pn[i] += e * val;
            }
        }
    }
#pragma unroll
    for (int mk2 = 1; mk2 < 16; mk2 <<= 1) {
#pragma unroll
        for (int i = 0; i < 4; ++i) {
            float mo = __shfl_xor(pm[i], mk2);
            float d2 = __shfl_xor(pd[i], mk2);
            float n2 = __shfl_xor(pn[i], mk2);
            float M = fmaxf(pm[i], mo);
            float e1 = __expf(pm[i] - M), e2 = __expf(mo - M);
            pd[i] = pd[i] * e1 + d2 * e2;
            pn[i] = pn[i] * e1 + n2 * e2;
            pm[i] = M;
        }
    }
    if (tn == 0) {
#pragma unroll
        for (int i = 0; i < 4; ++i) {
            int b = tb * 4 + i;
            *(float4*)&p.partials[(size_t)(b * NTILES + tile) * 4] = make_float4(pm[i], pd[i], pn[i], 0.f);
        }
    }
}

__global__ __launch_bounds__(256, 2) void fused_kernel(KParams p) {
    __shared__ __align__(16) float sm[9280];
    int blk = blockIdx.x, tid = threadIdx.x;
    unsigned bar = 0;

    // ---------------- P0: zero mem + transposes + costab + wv_out/vconst/qconst + detect ----
    {
        int gtid = blk * 256 + tid;
        float4* m4 = (float4*)p.mem;
        float4 z4 = make_float4(0.f, 0.f, 0.f, 0.f);
        for (int i = gtid; i < (NN * LAT) / 4; i += NBLK * 256) m4[i] = z4;
        if (blk < 256) {
            const int GS = 256 * 256;
            for (int i = gtid; i < 129 * 384; i += GS) { int d = i / 384, j = i % 384; p.W_ihT[i] = p.W_ih[j * 129 + d]; }
            for (int i = gtid; i < 128 * 384; i += GS) { int l = i / 384, j = i % 384; p.W_hhT[i] = p.W_hh[j * 128 + l]; }
            for (int pp = gtid; pp <= KTAB; pp += GS) {
                float tv = (float)pp * (1.0f / KTAB);
                for (int l = 0; l < 128; ++l) p.costab[l * CSTRIDE + pp] = __cosf(tv * p.tw[l] + p.tb_[l]);
            }
        } else if (blk == 256) {
            for (int d = tid; d < DH; d += 256) {
                float a = 0.f;
                for (int j = 0; j < LAT; ++j) a += p.Wv[d * LAT + j] * p.W_out[j];
                p.wv_out[d] = a;
            }
            if (tid == 0) {
                float a = p.b_out[0];
                for (int j = 0; j < LAT; ++j) a += p.bv[j] * p.W_out[j];
                p.vconst[0] = a;
            }
            if (tid < 128) {
                float a = p.bq[tid];
                for (int j = 0; j < 128; ++j) a += __cosf(p.tb_[j]) * p.Wq[(129 + j) * LAT + tid];
                p.qconst[tid] = a;
            }
            int* smi = (int*)sm;
            if (tid == 0) { smi[0] = 0; smi[1] = 0; }
            __syncthreads();
            const int* mask = (const int*)p.maskp;
            for (int i = tid; i < 4096; i += 256) {
                int v = mask[i];
                if ((unsigned)v > 1u) atomicOr(&smi[0], 1);
                if (v == 0x3F800000) atomicOr(&smi[1], 1);
            }
            __syncthreads();
            if (tid == 0) p.modep[0] = smi[1] ? 2 : (smi[0] ? 1 : 0);
        }
    }
    gbar(p.barcnt, (++bar) * NBLK);

    // ---------------- P1: setup2 (131 units) + gtab (5 units) + GRU s=0 (128 units) ---------
    {
        if (blk < 131) {
            float* vrow = sm;   // 128
            if (blk < 128) {    // BT row l
                int l = blk;
                if (tid < 128) vrow[tid] = p.Wq[(1 + l) * LAT + tid];
                __syncthreads();
                for (int d = tid; d < DH; d += 256) {
                    const float* wkr = p.Wk + d * LAT;
                    float a = 0.f;
#pragma unroll 4
                    for (int j = 0; j < 128; ++j) a += wkr[j] * vrow[j];
                    p.BT[l * 260 + d] = a;
                }
            } else if (blk == 128) {    // uc = Wk @ qconst
                if (tid < 128) vrow[tid] = p.qconst[tid];
                __syncthreads();
                for (int d = tid; d < DH; d += 256) {
                    const float* wkr = p.Wk + d * LAT;
                    float a = 0.f;
#pragma unroll 4
                    for (int j = 0; j < 128; ++j) a += wkr[j] * vrow[j];
                    p.uc[d] = a;
                }
            } else if (blk == 129) {    // kw0 = Wk @ Wq[0,:]
                if (tid < 128) vrow[tid] = p.Wq[tid];
                __syncthreads();
                for (int d = tid; d < DH; d += 256) {
                    const float* wkr = p.Wk + d * LAT;
                    float a = 0.f;
#pragma unroll 4
                    for (int j = 0; j < 128; ++j) a += wkr[j] * vrow[j];
                    p.kw0[d] = a;
                }
            } else {                    // abk + scal
                if (tid < 128) vrow[tid] = p.bk[tid];
                __syncthreads();
                if (tid < 128) {
                    const float* wqr = p.Wq + (1 + tid) * LAT;
                    float a = 0.f;
#pragma unroll 4
                    for (int j = 0; j < 128; ++j) a += wqr[j] * vrow[j];
                    p.abk[tid] = a;
                } else if (tid == 128) {
                    float a = 0.f;
                    for (int j = 0; j < 128; ++j) a += p.qconst[j] * p.bk[j];
                    p.scal[0] = a;
                } else if (tid == 129) {
                    float a = 0.f;
                    for (int j = 0; j < 128; ++j) a += p.Wq[j] * p.bk[j];
                    p.scal[1] = a;
                }
            }
        } else if (blk < 136) {     // gtab
            float* wv_s = sm;
            if (tid < LAT) wv_s[tid] = p.wv_out[129 + tid];
            __syncthreads();
            int pp = (blk - 131) * 256 + tid;
            if (pp <= KTAB) {
                float a = 0.f;
                for (int l = 0; l < 128; ++l) a += wv_s[l] * p.costab[l * CSTRIDE + pp];
                p.gtab[pp] = a;
            }
        } else if (blk < 264) {     // GRU rows for s=0 (h = 0)
            do_gru_row256(blk - 136, tid, 0, 1, p.x, p.t, p.source, p.target, p.tw, p.tb_,
                          p.W_ihT, p.W_hhT, p.b_ih, p.b_hh, p.mem, p.newh, sm);
        }
    }
    gbar(p.barcnt, (++bar) * NBLK);

    // ---------------- main loop: A-phase | bar | B-phase | bar ----------------
    for (int s = 0; s < S_LEN; ++s) {
        if (blk < 64) {
            a_work256(p, sm, blk, s);
        } else if (blk == 64) {
            scatter256(p, sm, s);
        } else if (blk == 65) {
            if (s > 0) do_combine(p.partials, p.vconst, p.out, s - 1, tid);
        }
        gbar(p.barcnt, (++bar) * NBLK);
        if (blk < NTILES) {
            attn_tile256(p, sm, blk, s);
        } else {
            if (s < S_LEN - 1)
                do_gru_row256(blk - NTILES, tid, s + 1, 0, p.x, p.t, p.source, p.target,
                              p.tw, p.tb_, p.W_ihT, p.W_hhT, p.b_ih, p.b_hh, p.mem, p.newh, sm);
        }
        gbar(p.barcnt, (++bar) * NBLK);
    }
    if (blk == 0) do_combine(p.partials, p.vconst, p.out, S_LEN - 1, tid);
}

// ============================================================================================
// Fallback path: the previous verified multi-kernel implementation (used only if the
// cooperative launch is rejected by the runtime).
// ============================================================================================
__global__ __launch_bounds__(256) void setup_all_kernel(
    const float* __restrict__ W_ih, const float* __restrict__ W_hh,
    const float* __restrict__ tw, const float* __restrict__ tb_,
    const float* __restrict__ Wq, const float* __restrict__ bq,
    const float* __restrict__ Wv, const float* __restrict__ bv,
    const float* __restrict__ W_out, const float* __restrict__ b_out,
    const int* __restrict__ mask,
    float* __restrict__ W_ihT, float* __restrict__ W_hhT,
    float* __restrict__ costab, float* __restrict__ wv_out, float* __restrict__ vconst,
    float* __restrict__ qconst, int* __restrict__ modep) {
    int blk = blockIdx.x, tid = threadIdx.x;
    if (blk < 256) {
        int gtid = blk * 256 + tid;
        const int GS = 256 * 256;
        for (int i = gtid; i < 129 * 384; i += GS) { int d = i / 384, j = i % 384; W_ihT[i] = W_ih[j * 129 + d]; }
        for (int i = gtid; i < 128 * 384; i += GS) { int l = i / 384, j = i % 384; W_hhT[i] = W_hh[j * 128 + l]; }
        for (int p = gtid; p <= KTAB; p += GS) {
            float tv = (float)p * (1.0f / KTAB);
            for (int l = 0; l < 128; ++l) costab[l * CSTRIDE + p] = __cosf(tv * tw[l] + tb_[l]);
        }
    } else {
        for (int d = tid; d < DH; d += 256) {
            float a = 0.f;
            for (int j = 0; j < LAT; ++j) a += Wv[d * LAT + j] * W_out[j];
            wv_out[d] = a;
        }
        if (tid == 0) {
            float a = b_out[0];
            for (int j = 0; j < LAT; ++j) a += bv[j] * W_out[j];
            *vconst = a;
        }
        if (tid < 128) {
            float a = bq[tid];
            for (int j = 0; j < 128; ++j) a += __cosf(tb_[j]) * Wq[(129 + j) * LAT + tid];
            qconst[tid] = a;
        }
        __shared__ int hasHigh, hasFloat;
        if (tid == 0) { hasHigh = 0; hasFloat = 0; }
        __syncthreads();
        for (int i = tid; i < 4096; i += 256) {
            int v = mask[i];
            if ((unsigned)v > 1u) atomicOr(&hasHigh, 1);
            if (v == 0x3F800000) atomicOr(&hasFloat, 1);
        }
        __syncthreads();
        if (tid == 0) *modep = hasFloat ? 2 : (hasHigh ? 1 : 0);
    }
}

__global__ __launch_bounds__(256) void setup2_kernel(
    const float* __restrict__ Wk, const float* __restrict__ Wq,
    const float* __restrict__ bk, const float* __restrict__ qconst,
    float* __restrict__ BT, float* __restrict__ uc, float* __restrict__ kw0,
    float* __restrict__ abk, float* __restrict__ scal) {
    int blk = blockIdx.x, tid = threadIdx.x;
    __shared__ float vrow[128];
    if (blk < 128) {
        int l = blk;
        if (tid < 128) vrow[tid] = Wq[(1 + l) * LAT + tid];
        __syncthreads();
        for (int d = tid; d < DH; d += 256) {
            const float* wkr = Wk + d * LAT;
            float a = 0.f;
#pragma unroll 4
            for (int j = 0; j < 128; ++j) a += wkr[j] * vrow[j];
            BT[l * 260 + d] = a;
        }
    } else if (blk == 128) {
        if (tid < 128) vrow[tid] = qconst[tid];
        __syncthreads();
        for (int d = tid; d < DH; d += 256) {
            const float* wkr = Wk + d * LAT;
            float a = 0.f;
#pragma unroll 4
            for (int j = 0; j < 128; ++j) a += wkr[j] * vrow[j];
            uc[d] = a;
        }
    } else if (blk == 129) {
        if (tid < 128) vrow[tid] = Wq[tid];
        __syncthreads();
        for (int d = tid; d < DH; d += 256) {
            const float* wkr = Wk + d * LAT;
            float a = 0.f;
#pragma unroll 4
            for (int j = 0; j < 128; ++j) a += wkr[j] * vrow[j];
            kw0[d] = a;
        }
    } else {
        if (tid < 128) vrow[tid] = bk[tid];
        __syncthreads();
        if (tid < 128) {
            const float* wqr = Wq + (1 + tid) * LAT;
            float a = 0.f;
#pragma unroll 4
            for (int j = 0; j < 128; ++j) a += wqr[j] * vrow[j];
            abk[tid] = a;
        } else if (tid == 128) {
            float a = 0.f;
            for (int j = 0; j < 128; ++j) a += qconst[j] * bk[j];
            scal[0] = a;
        } else if (tid == 129) {
            float a = 0.f;
            for (int j = 0; j < 128; ++j) a += Wq[j] * bk[j];
            scal[1] = a;
        }
    }
}

__global__ __launch_bounds__(256) void pre_kernel(
    const float* __restrict__ x, const float* __restrict__ t,
    const int* __restrict__ source, const int* __restrict__ target,
    const float* __restrict__ tw, const float* __restrict__ tb_,
    const float* __restrict__ W_ihT, const float* __restrict__ W_hhT,
    const float* __restrict__ b_ih, const float* __restrict__ b_hh,
    const float* __restrict__ mem, float* __restrict__ newh,
    const float* __restrict__ wv_out, const float* __restrict__ costab,
    float* __restrict__ gtab) {
    __shared__ __align__(16) float sm[1028];
    int blk = blockIdx.x, tid = threadIdx.x;
    if (blk < 5) {
        __shared__ float wv_s[LAT];
        if (tid < LAT) wv_s[tid] = wv_out[129 + tid];
        __syncthreads();
        int p = blk * 256 + tid;
        if (p <= KTAB) {
            float a = 0.f;
            for (int l = 0; l < 128; ++l) a += wv_s[l] * costab[l * CSTRIDE + p];
            gtab[p] = a;
        }
        return;
    }
    int r = blk - 5;
    do_gru_row256(r, tid, 0, 0, x, t, source, target, tw, tb_,
                  W_ihT, W_hhT, b_ih, b_hh, mem, newh, sm);
}

__global__ __launch_bounds__(512) void step_a3_kernel(
    const float* __restrict__ x, const int* __restrict__ source, const int* __restrict__ target,
    const float* __restrict__ BT, const float* __restrict__ uc, const float* __restrict__ kw0,
    const float* __restrict__ abk, const float* __restrict__ scal,
    const float* __restrict__ newh, float* __restrict__ mem,
    float* __restrict__ u0_g, float* __restrict__ qbk_g, float* __restrict__ uT,
    float* __restrict__ ftab, const float* __restrict__ costab,
    const float* __restrict__ partials, const float* __restrict__ vconst,
    float* __restrict__ out, int s) {
    int blk = blockIdx.x;
    int tid = threadIdx.x;
    if (blk == 64) {
        __shared__ int idxs[128];
        __shared__ int alive[128];
        if (tid < 128) idxs[tid] = (tid < 64) ? source[s * BSZ + tid] : target[s * BSZ + (tid - 64)];
        __syncthreads();
        if (tid < 128) {
            int i2 = idxs[tid];
            int a = 1;
            for (int r2 = tid + 1; r2 < 128; ++r2)
                if (idxs[r2] == i2) { a = 0; break; }
            alive[tid] = a;
        }
        __syncthreads();
        int row = tid >> 2, q4 = tid & 3;
        if (alive[row]) {
            const float4* srcp = (const float4*)(newh + row * LAT + q4 * 32);
            float4* dstp = (float4*)(mem + (size_t)idxs[row] * LAT + q4 * 32);
#pragma unroll
            for (int j = 0; j < 8; ++j) dstp[j] = srcp[j];
        }
        return;
    }
    if (blk == 65) {
        if (s > 0) do_combine(partials, vconst, out, s - 1, tid);
        return;
    }
    int b = blk;
    __shared__ float memv[128];
    __shared__ float udt_s[128];
    __shared__ float upart[4][260];
    __shared__ float red[8];
    __shared__ __align__(16) float fpart[3 * 1024];
    __shared__ int s_last;
    __shared__ float xvs;
    if (tid < 64) {
        unsigned long long mball = __ballot(target[s * BSZ + tid] == target[s * BSZ + b]);
        if (tid == 0) {
            s_last = 63 - __builtin_clzll(mball);
            xvs = x[(size_t)(s * BSZ + b) * NN + target[s * BSZ + b]];
        }
    }
    __syncthreads();
    if (tid < 128) memv[tid] = newh[(64 + s_last) * LAT + tid];
    __syncthreads();
    float xv = xvs;
    {
        int dd = tid & 127, kc = tid >> 7;
        int l0 = kc * 32;
        for (int d = dd; d < DH; d += 128) {
            float a = 0.f;
#pragma unroll 4
            for (int l = l0; l < l0 + 32; ++l) a += memv[l] * BT[l * 260 + d];
            upart[kc][d] = a;
        }
    }
    __syncthreads();
    if (tid < 257) {
        float a = uc[tid] + xv * kw0[tid] + upart[0][tid] + upart[1][tid] + upart[2][tid] + upart[3][tid];
        if (tid == 0) u0_g[b] = a;
        else if (tid <= 128) uT[(tid - 1) * BSZ + b] = a;
        else udt_s[tid - 129] = a;
    }
    if (tid >= 448) {
        int i = tid - 448;
        float a = memv[i] * abk[i] + memv[64 + i] * abk[64 + i];
        for (int off = 32; off; off >>= 1) a += __shfl_down(a, off, 64);
        if (i == 0) qbk_g[b] = scal[0] + xv * scal[1] + a;
    }
    __syncthreads();
    {
        int pi = tid & 127, lc = tid >> 7;
        int l0 = lc * 32;
        float a0x = 0.f, a0y = 0.f, a0z = 0.f, a0w = 0.f;
        float a1x = 0.f, a1y = 0.f, a1z = 0.f, a1w = 0.f;
#pragma unroll 4
        for (int l = l0; l < l0 + 32; ++l) {
            float ul = udt_s[l];
            const float* cp = &costab[l * CSTRIDE + pi * 8];
            float4 c0 = *(const float4*)cp;
            float4 c1 = *(const float4*)(cp + 4);
            a0x += ul * c0.x; a0y += ul * c0.y; a0z += ul * c0.z; a0w += ul * c0.w;
            a1x += ul * c1.x; a1y += ul * c1.y; a1z += ul * c1.z; a1w += ul * c1.w;
        }
        if (lc) {
            float* fp = &fpart[(lc - 1) * 1024 + pi * 8];
            *(float4*)fp = make_float4(a0x, a0y, a0z, a0w);
            *(float4*)(fp + 4) = make_float4(a1x, a1y, a1z, a1w);
        }
        if (pi == 127) {
            float a = 0.f;
            for (int l = l0; l < l0 + 32; ++l) a += udt_s[l] * costab[l * CSTRIDE + KTAB];
            red[lc] = a;
        }
        __syncthreads();
        if (lc == 0) {
            for (int c = 0; c < 3; ++c) {
                const float* fp = &fpart[c * 1024 + pi * 8];
                a0x += fp[0]; a0y += fp[1]; a0z += fp[2]; a0w += fp[3];
                a1x += fp[4]; a1y += fp[5]; a1z += fp[6]; a1w += fp[7];
            }
            float* fo = &ftab[b * FSTRIDE + pi * 8];
            *(float4*)fo = make_float4(a0x, a0y, a0z, a0w);
            *(float4*)(fo + 4) = make_float4(a1x, a1y, a1z, a1w);
        }
        if (tid == 0) ftab[b * FSTRIDE + KTAB] = red[0] + red[1] + red[2] + red[3];
    }
}

__global__ __launch_bounds__(256) void step_b2_kernel(
    const float* __restrict__ x, const float* __restrict__ t,
    const void* __restrict__ maskp, const int* __restrict__ modep,
    const int* __restrict__ source, const int* __restrict__ target,
    const float* __restrict__ tw, const float* __restrict__ tb_,
    const float* __restrict__ W_ihT, const float* __restrict__ W_hhT,
    const float* __restrict__ b_ih, const float* __restrict__ b_hh,
    const float* __restrict__ mem, float* __restrict__ newh,
    const float* __restrict__ uT, const float* __restrict__ u0_g,
    const float* __restrict__ qbk_g, const float* __restrict__ ftab,
    const float* __restrict__ gtab, const float* __restrict__ wv_out,
    float* __restrict__ partials, int s) {
    int blk = blockIdx.x, tid = threadIdx.x;
    __shared__ __align__(16) float sm[9280];
    if (blk >= NTILES) {
        if (s < S_LEN - 1) {
            int r = blk - NTILES;
            do_gru_row256(r, tid, s + 1, 0, x, t, source, target, tw, tb_,
                          W_ihT, W_hhT, b_ih, b_hh, mem, newh, sm);
        }
        return;
    }
    KParams p;
    p.x = x; p.t = t; p.maskp = maskp; p.modep = (int*)modep;
    p.mem = (float*)mem; p.uT = (float*)uT; p.u0_g = (float*)u0_g; p.qbk_g = (float*)qbk_g;
    p.ftab = (float*)ftab; p.gtab = (float*)gtab; p.wv_out = (float*)wv_out;
    p.partials = (float*)partials;
    attn_tile256(p, sm, blk, s);
}

__global__ __launch_bounds__(64) void tail_kernel(const float* __restrict__ partials,
                                                  const float* __restrict__ vconst,
                                                  float* __restrict__ out) {
    do_combine(partials, vconst, out, S_LEN - 1, threadIdx.x);
}

extern "C" void kernel_launch(void* const* d_in, const int* in_sizes, int n_in,
                              void* d_out, int out_size, void* d_ws, size_t ws_size,
                              hipStream_t stream) {
    const float* x      = (const float*)d_in[0];
    const float* t      = (const float*)d_in[1];
    const int*   source = (const int*)d_in[2];
    const int*   target = (const int*)d_in[3];
    const void*  maskp  = (const void*)d_in[4];
    const float* tw     = (const float*)d_in[5];
    const float* tb     = (const float*)d_in[6];
    const float* W_ih   = (const float*)d_in[7];
    const float* W_hh   = (const float*)d_in[8];
    const float* b_ih   = (const float*)d_in[9];
    const float* b_hh   = (const float*)d_in[10];
    const float* Wq     = (const float*)d_in[11];
    const float* bq     = (const float*)d_in[12];
    const float* Wk     = (const float*)d_in[13];
    const float* bk     = (const float*)d_in[14];
    const float* Wv     = (const float*)d_in[15];
    const float* bv     = (const float*)d_in[16];
    const float* W_out  = (const float*)d_in[17];
    const float* b_out  = (const float*)d_in[18];
    float* out = (float*)d_out;

    float* w = (float*)d_ws;
    float* mem    = w; w += (size_t)NN * LAT;
    float* newh   = w; w += 128 * LAT;
    float* uT     = w; w += LAT * BSZ;
    float* u0_g   = w; w += BSZ;
    float* qbk_g  = w; w += BSZ;
    float* ftab   = w; w += BSZ * FSTRIDE;
    float* gtab   = w; w += FSTRIDE;
    float* costab = w; w += LAT * CSTRIDE;
    float* partials = w; w += (size_t)BSZ * NTILES * 4;
    float* wv_out = w; w += 260;
    float* vconst = w; w += 4;
    float* W_ihT  = w; w += 129 * 384;
    float* W_hhT  = w; w += 128 * 384;
    float* BT     = w; w += 128 * 260;
    float* uc     = w; w += 260;
    float* kw0    = w; w += 260;
    float* abk    = w; w += 128;
    float* qconst = w; w += 128;
    float* scal   = w; w += 8;
    int*   modep  = (int*)w; w += 4;
    unsigned* barcnt = (unsigned*)w; w += 4;

    KParams kp;
    kp.x = x; kp.t = t; kp.source = source; kp.target = target; kp.maskp = maskp;
    kp.tw = tw; kp.tb_ = tb;
    kp.W_ih = W_ih; kp.W_hh = W_hh; kp.b_ih = b_ih; kp.b_hh = b_hh;
    kp.Wq = Wq; kp.bq = bq; kp.Wk = Wk; kp.bk = bk; kp.Wv = Wv; kp.bv = bv;
    kp.W_out = W_out; kp.b_out = b_out;
    kp.out = out;
    kp.mem = mem; kp.newh = newh; kp.uT = uT; kp.u0_g = u0_g; kp.qbk_g = qbk_g;
    kp.ftab = ftab; kp.gtab = gtab; kp.costab = costab; kp.partials = partials;
    kp.wv_out = wv_out; kp.vconst = vconst; kp.W_ihT = W_ihT; kp.W_hhT = W_hhT;
    kp.BT = BT; kp.uc = uc; kp.kw0 = kw0; kp.abk = abk; kp.qconst = qconst; kp.scal = scal;
    kp.modep = modep;
    kp.barcnt = barcnt;

    hipMemsetAsync(barcnt, 0, sizeof(unsigned), stream);

    void* args[] = { &kp };
    hipError_t err = hipLaunchCooperativeKernel((const void*)fused_kernel,
                                                dim3(NBLK), dim3(256), args, 0, stream);
    if (err != hipSuccess) {
        // Fallback: previous verified multi-kernel path.
        hipMemsetAsync(mem, 0, (size_t)NN * LAT * sizeof(float), stream);
        setup_all_kernel<<<257, 256, 0, stream>>>(W_ih, W_hh, tw, tb, Wq, bq, Wv, bv, W_out, b_out,
                                                  (const int*)maskp, W_ihT, W_hhT,
                                                  costab, wv_out, vconst, qconst, modep);
        setup2_kernel<<<131, 256, 0, stream>>>(Wk, Wq, bk, qconst, BT, uc, kw0, abk, scal);
        pre_kernel<<<133, 256, 0, stream>>>(x, t, source, target, tw, tb,
                                            W_ihT, W_hhT, b_ih, b_hh, mem, newh,
                                            wv_out, costab, gtab);
        for (int s = 0; s < S_LEN; ++s) {
            step_a3_kernel<<<66, 512, 0, stream>>>(x, source, target, BT, uc, kw0, abk, scal,
                                                   newh, mem, u0_g, qbk_g, uT, ftab, costab,
                                                   partials, vconst, out, s);
            step_b2_kernel<<<NTILES + 128, 256, 0, stream>>>(x, t, maskp, modep, source, target,
                                                             tw, tb, W_ihT, W_hhT, b_ih, b_hh,
                                                             mem, newh, uT, u0_g, qbk_g,
                                                             ftab, gtab, wv_out, partials, s);
        }
        tail_kernel<<<1, 64, 0, stream>>>(partials, vconst, out);
    }
}

// Round 4
// 1640.170 us; speedup vs baseline: 1.6339x; 1.4485x over previous
//
#include <hip/hip_runtime.h>
#include <math.h>

#define S_LEN 16
#define BSZ   64
#define NN    10000
#define LAT   128
#define DH    257
#define KTAB  1024
#define CSTRIDE (KTAB + 8)    // costab leading dim
#define FSTRIDE (KTAB + 4)    // ftab leading dim
#define NTILE 64
#define NTILES 157            // ceil(10000/64)
#define NBLK  (NTILES + 128)  // 285 fused grid
#define GRPS  16
#define GW    18              // barrier group width (last group = 285-15*18 = 15)
#define SCALE 0.08838834764831845f
#define NEG1E9 -1000000000.0f

// Native clang vector type: first-class register tuple for inline-asm "v" constraints.
typedef float v4f __attribute__((ext_vector_type(4)));

// ============================================================================================
// System-coherent (bypass L1+L2, coherent at MALL) access helpers. Offsets in FLOAT units
// relative to a wave-uniform base pointer (SGPR pair via "s").
// ============================================================================================
__device__ __forceinline__ float ld_f1(const float* base, int idx) {
    float r; unsigned off = (unsigned)idx << 2;
    asm volatile("global_load_dword %0, %1, %2 sc0 sc1\n\ts_waitcnt vmcnt(0)"
                 : "=&v"(r) : "v"(off), "s"(base) : "memory");
    return r;
}
__device__ __forceinline__ v4f ld_f4(const float* base, int idx) {
    v4f r; unsigned off = (unsigned)idx << 2;
    asm volatile("global_load_dwordx4 %0, %1, %2 sc0 sc1\n\ts_waitcnt vmcnt(0)"
                 : "=&v"(r) : "v"(off), "s"(base) : "memory");
    return r;
}
__device__ __forceinline__ void ld_2(const float* base, int i0, int i1, float& a, float& b) {
    unsigned o0 = (unsigned)i0 << 2, o1 = (unsigned)i1 << 2;
    asm volatile("global_load_dword %0, %2, %4 sc0 sc1\n\t"
                 "global_load_dword %1, %3, %4 sc0 sc1\n\t"
                 "s_waitcnt vmcnt(0)"
                 : "=&v"(a), "=&v"(b) : "v"(o0), "v"(o1), "s"(base) : "memory");
}
__device__ __forceinline__ void ld_f4x4(const float* base, int i0, int i1, int i2, int i3,
                                        v4f& a, v4f& b, v4f& c, v4f& d) {
    unsigned o0 = (unsigned)i0 << 2, o1 = (unsigned)i1 << 2;
    unsigned o2 = (unsigned)i2 << 2, o3 = (unsigned)i3 << 2;
    asm volatile("global_load_dwordx4 %0, %4, %8 sc0 sc1\n\t"
                 "global_load_dwordx4 %1, %5, %8 sc0 sc1\n\t"
                 "global_load_dwordx4 %2, %6, %8 sc0 sc1\n\t"
                 "global_load_dwordx4 %3, %7, %8 sc0 sc1\n\t"
                 "s_waitcnt vmcnt(0)"
                 : "=&v"(a), "=&v"(b), "=&v"(c), "=&v"(d)
                 : "v"(o0), "v"(o1), "v"(o2), "v"(o3), "s"(base) : "memory");
}
// 16 scalar loads: 8 offsets, each loads [off] and [off+4B] (ftab interp pairs)
__device__ __forceinline__ void ld_ft16(const float* base,
    unsigned o0, unsigned o1, unsigned o2, unsigned o3,
    unsigned o4, unsigned o5, unsigned o6, unsigned o7,
    float& a0, float& b0, float& a1, float& b1, float& a2, float& b2, float& a3, float& b3,
    float& a4, float& b4, float& a5, float& b5, float& a6, float& b6, float& a7, float& b7) {
    asm volatile(
        "global_load_dword %0, %16, %24 sc0 sc1\n\t"
        "global_load_dword %1, %16, %24 offset:4 sc0 sc1\n\t"
        "global_load_dword %2, %17, %24 sc0 sc1\n\t"
        "global_load_dword %3, %17, %24 offset:4 sc0 sc1\n\t"
        "global_load_dword %4, %18, %24 sc0 sc1\n\t"
        "global_load_dword %5, %18, %24 offset:4 sc0 sc1\n\t"
        "global_load_dword %6, %19, %24 sc0 sc1\n\t"
        "global_load_dword %7, %19, %24 offset:4 sc0 sc1\n\t"
        "global_load_dword %8, %20, %24 sc0 sc1\n\t"
        "global_load_dword %9, %20, %24 offset:4 sc0 sc1\n\t"
        "global_load_dword %10, %21, %24 sc0 sc1\n\t"
        "global_load_dword %11, %21, %24 offset:4 sc0 sc1\n\t"
        "global_load_dword %12, %22, %24 sc0 sc1\n\t"
        "global_load_dword %13, %22, %24 offset:4 sc0 sc1\n\t"
        "global_load_dword %14, %23, %24 sc0 sc1\n\t"
        "global_load_dword %15, %23, %24 offset:4 sc0 sc1\n\t"
        "s_waitcnt vmcnt(0)"
        : "=&v"(a0), "=&v"(b0), "=&v"(a1), "=&v"(b1), "=&v"(a2), "=&v"(b2), "=&v"(a3), "=&v"(b3),
          "=&v"(a4), "=&v"(b4), "=&v"(a5), "=&v"(b5), "=&v"(a6), "=&v"(b6), "=&v"(a7), "=&v"(b7)
        : "v"(o0), "v"(o1), "v"(o2), "v"(o3), "v"(o4), "v"(o5), "v"(o6), "v"(o7), "s"(base)
        : "memory");
}
__device__ __forceinline__ void st_f1(float* base, int idx, float v) {
    unsigned off = (unsigned)idx << 2;
    asm volatile("global_store_dword %0, %1, %2 sc0 sc1"
                 :: "v"(off), "v"(v), "s"(base) : "memory");
}
__device__ __forceinline__ void st_f4(float* base, int idx, v4f v) {
    unsigned off = (unsigned)idx << 2;
    asm volatile("global_store_dwordx4 %0, %1, %2 sc0 sc1"
                 :: "v"(off), "v"(v), "s"(base) : "memory");
}

// ============================================================================================
// Fence-free grid barrier. Two-level: 16 group counters -> global counter -> 16 release words.
// Mutable data coherence comes from sc0sc1 accesses; arrival only needs vmcnt drained.
// ctr layout (unsigned, stride 64 words = 256B): grp g at g*64 (g<16); global at 16*64;
// release g at (17+g)*64.
// ============================================================================================
__device__ __forceinline__ void gbar_fast(unsigned* ctr, int grp, unsigned gsz, unsigned k) {
    asm volatile("s_waitcnt vmcnt(0) lgkmcnt(0)" ::: "memory");
    __syncthreads();
    if (threadIdx.x == 0) {
        unsigned old = __hip_atomic_fetch_add(ctr + grp * 64, 1u,
                                              __ATOMIC_RELAXED, __HIP_MEMORY_SCOPE_AGENT);
        if (old == k * gsz - 1u) {
            unsigned og = __hip_atomic_fetch_add(ctr + GRPS * 64, 1u,
                                                 __ATOMIC_RELAXED, __HIP_MEMORY_SCOPE_AGENT);
            if (og == k * GRPS - 1u) {
#pragma unroll
                for (int g = 0; g < GRPS; ++g)
                    __hip_atomic_store(ctr + (GRPS + 1 + g) * 64, k,
                                       __ATOMIC_RELAXED, __HIP_MEMORY_SCOPE_AGENT);
            }
        }
        while (__hip_atomic_load(ctr + (GRPS + 1 + grp) * 64,
                                 __ATOMIC_RELAXED, __HIP_MEMORY_SCOPE_AGENT) < k)
            __builtin_amdgcn_s_sleep(1);
    }
    __syncthreads();
    asm volatile("" ::: "memory");
}

// ============================================================================================
struct KParams {
    const float *x, *t;
    const int *source, *target;
    const void *maskp;
    const float *tw, *tb_;
    const float *W_ih, *W_hh, *b_ih, *b_hh;
    const float *Wq, *bq, *Wk, *bk, *Wv, *bv, *W_out, *b_out;
    float *out;
    float *mem, *newh, *uT, *u0_g, *qbk_g, *ftab, *gtab, *costab, *partials;
    float *wv_out, *vconst, *W_ihT, *W_hhT, *BT, *uc, *kw0, *abk, *qconst, *scal;
    int *modep;
    unsigned *barcnt;
};

// ================= GRU one row, 256 threads. mem/newh via sc; tables cached ====
__device__ __forceinline__ void do_gru_sc(int r, int tid2, int s, int zeroH,
                                          const KParams& p, float* sm) {
    float* msg = sm;          // 132
    float* h   = sm + 132;    // 128
    float* gi3 = sm + 260;    // 384
    float* gh3 = sm + 644;    // 384
    int b = r & 63;
    int idx = (r < 64) ? p.source[s * BSZ + b] : p.target[s * BSZ + b];
    const float* xs = p.x + (size_t)(s * BSZ + b) * NN;
    const float* ts = p.t + (size_t)(s * BSZ + b) * NN;
    if (tid2 == 0) msg[0] = xs[idx];
    if (tid2 < 128) {
        float tv = ts[idx];
        msg[1 + tid2] = __cosf(tv * p.tw[tid2] + p.tb_[tid2]);
    }
    if (tid2 < 32) {
        v4f hv;
        if (zeroH) hv = (v4f){0.f, 0.f, 0.f, 0.f};
        else       hv = ld_f4(p.mem, idx * LAT + tid2 * 4);
        *(v4f*)&h[tid2 * 4] = hv;
    }
    __syncthreads();
    if (tid2 < 128) {
        int j = tid2;
        float a0 = p.b_ih[j], a1 = p.b_ih[128 + j], a2 = p.b_ih[256 + j];
#pragma unroll 4
        for (int d = 0; d < 129; ++d) {
            float m = msg[d];
            const float* col = p.W_ihT + d * 384;
            a0 += m * col[j]; a1 += m * col[128 + j]; a2 += m * col[256 + j];
        }
        gi3[j] = a0; gi3[128 + j] = a1; gi3[256 + j] = a2;
    } else {
        int j = tid2 - 128;
        float a0 = p.b_hh[j], a1 = p.b_hh[128 + j], a2 = p.b_hh[256 + j];
#pragma unroll 4
        for (int l = 0; l < 128; ++l) {
            float hv = h[l];
            const float* col = p.W_hhT + l * 384;
            a0 += hv * col[j]; a1 += hv * col[128 + j]; a2 += hv * col[256 + j];
        }
        gh3[j] = a0; gh3[128 + j] = a1; gh3[256 + j] = a2;
    }
    __syncthreads();
    if (tid2 < 128) {
        int j = tid2;
        float rr = 1.f / (1.f + __expf(-(gi3[j] + gh3[j])));
        float zz = 1.f / (1.f + __expf(-(gi3[128 + j] + gh3[128 + j])));
        float nn2 = tanhf(gi3[256 + j] + rr * gh3[256 + j]);
        st_f1(p.newh, r * LAT + j, (1.f - zz) * nn2 + zz * h[j]);
    }
}

// ================= combine for batch element b, full 256-thread block =================
__device__ __forceinline__ void combine_block(const KParams& p, int b, int ps, float* sm) {
    int tid = threadIdx.x;
    float m = -3.0e38f, d = 0.f, n = 0.f;
    if (tid < NTILES) {
        v4f v = ld_f4(p.partials, (b * NTILES + tid) * 4);
        m = v.x; d = v.y; n = v.z;
    }
#pragma unroll
    for (int off = 32; off; off >>= 1) {
        float mo = __shfl_down(m, off, 64);
        float d2 = __shfl_down(d, off, 64);
        float n2 = __shfl_down(n, off, 64);
        float M = fmaxf(m, mo);
        float e1 = __expf(m - M), e2 = __expf(mo - M);
        d = d * e1 + d2 * e2; n = n * e1 + n2 * e2; m = M;
    }
    __syncthreads();
    float* red = sm;   // 12 floats
    int w = tid >> 6;
    if ((tid & 63) == 0) { red[w * 3] = m; red[w * 3 + 1] = d; red[w * 3 + 2] = n; }
    __syncthreads();
    if (tid == 0) {
        float M = red[0], D = red[1], Nm = red[2];
        for (int k2 = 1; k2 < 4; ++k2) {
            float m2 = red[k2 * 3], d2 = red[k2 * 3 + 1], n2 = red[k2 * 3 + 2];
            float M2 = fmaxf(M, m2);
            float e1 = __expf(M - M2), e2 = __expf(m2 - M2);
            D = D * e1 + d2 * e2; Nm = Nm * e1 + n2 * e2; M = M2;
        }
        st_f1(p.out, ps * BSZ + b, Nm / D + p.vconst[0]);
    }
    __syncthreads();
}

// ---- A-phase per-b work, 256 threads ----
__device__ __forceinline__ void a_work256(const KParams& p, float* sm, int b, int s) {
    float* memv  = sm;            // 128
    float* udt_s = sm + 128;      // 128
    float* upart = sm + 256;      // 2*260 = 520
    float* red   = sm + 776;      // 2
    float* fpart = sm + 784;      // 1024 -> ends 1808
    float* xvs_p = sm + 1808;
    int*   slast_p = (int*)(sm + 1809);
    int tid = threadIdx.x;

    if (tid < 64) {
        unsigned long long mball = __ballot(p.target[s * BSZ + tid] == p.target[s * BSZ + b]);
        if (tid == 0) {
            *slast_p = 63 - __builtin_clzll(mball);
            *xvs_p = p.x[(size_t)(s * BSZ + b) * NN + p.target[s * BSZ + b]];
        }
    }
    __syncthreads();
    int s_last = *slast_p;
    if (tid < 32) {   // memv = newh[64+s_last] (post-scatter mem[tg]), sc
        v4f v = ld_f4(p.newh, (64 + s_last) * LAT + tid * 4);
        *(v4f*)&memv[tid * 4] = v;
    }
    __syncthreads();
    float xv = *xvs_p;
    {   // u[d] = uc[d] + xv*kw0[d] + sum_l memv[l]*BT[l*260+d], K split 2 ways (cached BT)
        int dd = tid & 127, kc = tid >> 7;
        int l0 = kc * 64;
        for (int d = dd; d < DH; d += 128) {
            float a = 0.f;
#pragma unroll 4
            for (int l = l0; l < l0 + 64; ++l) a += memv[l] * p.BT[l * 260 + d];
            upart[kc * 260 + d] = a;
        }
    }
    __syncthreads();
    {
        float a = p.uc[tid] + xv * p.kw0[tid] + upart[tid] + upart[260 + tid];
        if (tid == 0) st_f1(p.u0_g, b, a);
        else if (tid <= 128) st_f1(p.uT, (tid - 1) * BSZ + b, a);
        else udt_s[tid - 129] = a;                 // d = 129..255 -> udt_s[0..126]
        if (tid == 0) {                            // d = 256 -> udt_s[127]
            float a2 = p.uc[256] + xv * p.kw0[256] + upart[256] + upart[516];
            udt_s[127] = a2;
        }
    }
    if (tid >= 192) {   // qbk = scal0 + xv*scal1 + memv.abk  (one wave)
        int i = tid - 192;
        float a = memv[i] * p.abk[i] + memv[64 + i] * p.abk[64 + i];
        for (int off = 32; off; off >>= 1) a += __shfl_down(a, off, 64);
        if (i == 0) st_f1(p.qbk_g, b, p.scal[0] + xv * p.scal[1] + a);
    }
    __syncthreads();
    {   // ftab: 8 points/thread, L split 2 ways (cached costab)
        int pi = tid & 127, lc = tid >> 7;
        int l0 = lc * 64;
        float a0x = 0.f, a0y = 0.f, a0z = 0.f, a0w = 0.f;
        float a1x = 0.f, a1y = 0.f, a1z = 0.f, a1w = 0.f;
#pragma unroll 4
        for (int l = l0; l < l0 + 64; ++l) {
            float ul = udt_s[l];
            const float* cp = &p.costab[l * CSTRIDE + pi * 8];
            float4 c0 = *(const float4*)cp;
            float4 c1 = *(const float4*)(cp + 4);
            a0x += ul * c0.x; a0y += ul * c0.y; a0z += ul * c0.z; a0w += ul * c0.w;
            a1x += ul * c1.x; a1y += ul * c1.y; a1z += ul * c1.z; a1w += ul * c1.w;
        }
        if (lc) {
            float* fp = &fpart[pi * 8];
            *(float4*)fp = make_float4(a0x, a0y, a0z, a0w);
            *(float4*)(fp + 4) = make_float4(a1x, a1y, a1z, a1w);
        }
        if (pi == 127) {
            float a = 0.f;
            for (int l = l0; l < l0 + 64; ++l) a += udt_s[l] * p.costab[l * CSTRIDE + KTAB];
            red[lc] = a;
        }
        __syncthreads();
        if (lc == 0) {
            const float* fp = &fpart[pi * 8];
            a0x += fp[0]; a0y += fp[1]; a0z += fp[2]; a0w += fp[3];
            a1x += fp[4]; a1y += fp[5]; a1z += fp[6]; a1w += fp[7];
            st_f4(p.ftab, b * FSTRIDE + pi * 8,     (v4f){a0x, a0y, a0z, a0w});
            st_f4(p.ftab, b * FSTRIDE + pi * 8 + 4, (v4f){a1x, a1y, a1z, a1w});
        }
        if (tid == 0) st_f1(p.ftab, b * FSTRIDE + KTAB, red[0] + red[1]);
    }
}

// ---- scatter, 256 threads (2 threads/row), sc copies newh rows -> mem rows ----
__device__ __forceinline__ void scatter256(const KParams& p, float* sm, int s) {
    int* idxs  = (int*)sm;
    int* alive = idxs + 128;
    int tid = threadIdx.x;
    if (tid < 128) idxs[tid] = (tid < 64) ? p.source[s * BSZ + tid] : p.target[s * BSZ + (tid - 64)];
    __syncthreads();
    if (tid < 128) {
        int i2 = idxs[tid];
        int a = 1;
        for (int r2 = tid + 1; r2 < 128; ++r2)
            if (idxs[r2] == i2) { a = 0; break; }
        alive[tid] = a;
    }
    __syncthreads();
    int row = tid >> 1, q2 = tid & 1;
    if (alive[row]) {
        int src = row * LAT + q2 * 64;
        int dst = idxs[row] * LAT + q2 * 64;
#pragma unroll
        for (int g2 = 0; g2 < 4; ++g2) {
            v4f a, b, c, d;
            ld_f4x4(p.newh, src + g2 * 16, src + g2 * 16 + 4, src + g2 * 16 + 8, src + g2 * 16 + 12,
                    a, b, c, d);
            st_f4(p.mem, dst + g2 * 16,      a);
            st_f4(p.mem, dst + g2 * 16 + 4,  b);
            st_f4(p.mem, dst + g2 * 16 + 8,  c);
            st_f4(p.mem, dst + g2 * 16 + 12, d);
        }
    }
}

// ---- attention tile, 256 threads ----
__device__ __forceinline__ void attn_tile256(const KParams& p, float* sm, int tile, int s) {
    float* memT   = sm;           // 64*72 = 4608
    float* uTs    = sm + 4608;    // 64*68 = 4352
    float* memv_s = sm + 8960;    // 64
    float* wv_s   = sm + 9024;    // 128
    float* u0_s   = sm + 9152;    // 64
    float* qbk_s  = sm + 9216;    // 64  (total 9280)
    int tid = threadIdx.x;
    int n0 = tile * NTILE;
    int tb = tid >> 4, tn = tid & 15;
    int nvalid = NN - n0; if (nvalid > NTILE) nvalid = NTILE;

    if (tid < 128) wv_s[tid] = p.wv_out[1 + tid];
    if (tid < 64) {
        float a, b2;
        ld_2(p.u0_g, tid, 64 + tid, a, b2);   // qbk_g = u0_g + 64 (layout guarantee)
        u0_s[tid] = a; qbk_s[tid] = b2; memv_s[tid] = 0.f;
    }

    float acc[4][4];
#pragma unroll
    for (int i = 0; i < 4; ++i)
#pragma unroll
        for (int j = 0; j < 4; ++j) acc[i][j] = 0.f;

    for (int l0 = 0; l0 < 128; l0 += 64) {
        __syncthreads();
        {   // stage mem -> memT transposed (sc batched loads)
            int n_l = tid & 63, lq = (tid >> 6) * 16;
            if (n_l < nvalid) {
                int m0 = (n0 + n_l) * LAT + l0 + lq;
                v4f a0, a1, a2, a3;
                ld_f4x4(p.mem, m0, m0 + 4, m0 + 8, m0 + 12, a0, a1, a2, a3);
                memT[(lq + 0) * 72 + n_l] = a0.x; memT[(lq + 1) * 72 + n_l] = a0.y;
                memT[(lq + 2) * 72 + n_l] = a0.z; memT[(lq + 3) * 72 + n_l] = a0.w;
                memT[(lq + 4) * 72 + n_l] = a1.x; memT[(lq + 5) * 72 + n_l] = a1.y;
                memT[(lq + 6) * 72 + n_l] = a1.z; memT[(lq + 7) * 72 + n_l] = a1.w;
                memT[(lq + 8) * 72 + n_l] = a2.x; memT[(lq + 9) * 72 + n_l] = a2.y;
                memT[(lq + 10) * 72 + n_l] = a2.z; memT[(lq + 11) * 72 + n_l] = a2.w;
                memT[(lq + 12) * 72 + n_l] = a3.x; memT[(lq + 13) * 72 + n_l] = a3.y;
                memT[(lq + 14) * 72 + n_l] = a3.z; memT[(lq + 15) * 72 + n_l] = a3.w;
            } else {
                for (int j = 0; j < 16; ++j) memT[(lq + j) * 72 + n_l] = 0.f;
            }
        }
        {   // stage uT chunk -> uTs (sc batched loads)
            int bq4 = (tid & 15) * 4;
            int ll = (tid >> 4) * 4;
            int u0i = (l0 + ll) * BSZ + bq4;
            v4f v0, v1, v2, v3;
            ld_f4x4(p.uT, u0i, u0i + BSZ, u0i + 2 * BSZ, u0i + 3 * BSZ, v0, v1, v2, v3);
            *(v4f*)&uTs[(ll + 0) * 68 + bq4] = v0;
            *(v4f*)&uTs[(ll + 1) * 68 + bq4] = v1;
            *(v4f*)&uTs[(ll + 2) * 68 + bq4] = v2;
            *(v4f*)&uTs[(ll + 3) * 68 + bq4] = v3;
        }
        __syncthreads();
        if (tid < 64) {   // memv partial
            float a = memv_s[tid];
            for (int l = 0; l < 64; ++l) a += wv_s[l0 + l] * memT[l * 72 + tid];
            memv_s[tid] = a;
        }
        for (int l = 0; l < 64; ++l) {
            float4 uv = *(const float4*)&uTs[l * 68 + tb * 4];
            float4 mv = *(const float4*)&memT[l * 72 + tn * 4];
            acc[0][0] += uv.x * mv.x; acc[0][1] += uv.x * mv.y; acc[0][2] += uv.x * mv.z; acc[0][3] += uv.x * mv.w;
            acc[1][0] += uv.y * mv.x; acc[1][1] += uv.y * mv.y; acc[1][2] += uv.y * mv.z; acc[1][3] += uv.y * mv.w;
            acc[2][0] += uv.z * mv.x; acc[2][1] += uv.z * mv.y; acc[2][2] += uv.z * mv.z; acc[2][3] += uv.z * mv.w;
            acc[3][0] += uv.w * mv.x; acc[3][1] += uv.w * mv.y; acc[3][2] += uv.w * mv.z; acc[3][3] += uv.w * mv.w;
        }
    }
    __syncthreads();

    const float c0 = p.wv_out[0];
    int mode = p.modep[0];
    const int* m32 = (const int*)p.maskp;
    const unsigned char* m8 = (const unsigned char*)p.maskp;
    const float* mf = (const float*)p.maskp;

    float pm[4], pd[4], pn[4];
#pragma unroll
    for (int i = 0; i < 4; ++i) { pm[i] = -3.0e38f; pd[i] = 0.f; pn[i] = 0.f; }

#pragma unroll
    for (int ih = 0; ih < 2; ++ih) {
        float xv[2][4], fr[2][4], gv[2][4]; int mk[2][4], vl[2][4]; unsigned off[2][4];
#pragma unroll
        for (int u = 0; u < 2; ++u) {
            int i = ih * 2 + u, b = tb * 4 + i;
            size_t base = (size_t)(s * BSZ + b) * NN + n0 + tn * 4;
            float tv4[4];
            if (tn * 4 + 3 < nvalid) {
                float4 xx = *(const float4*)(p.x + base);
                float4 tt = *(const float4*)(p.t + base);
                xv[u][0] = xx.x; xv[u][1] = xx.y; xv[u][2] = xx.z; xv[u][3] = xx.w;
                tv4[0] = tt.x; tv4[1] = tt.y; tv4[2] = tt.z; tv4[3] = tt.w;
                if (mode == 1) {
                    unsigned mw = *(const unsigned*)(m8 + base);
                    mk[u][0] = mw & 0xff; mk[u][1] = (mw >> 8) & 0xff;
                    mk[u][2] = (mw >> 16) & 0xff; mk[u][3] = (mw >> 24) & 0xff;
                } else if (mode == 2) {
                    float4 mm = *(const float4*)(mf + base);
                    mk[u][0] = (mm.x != 0.f); mk[u][1] = (mm.y != 0.f);
                    mk[u][2] = (mm.z != 0.f); mk[u][3] = (mm.w != 0.f);
                } else {
                    int4 mm = *(const int4*)(m32 + base);
                    mk[u][0] = mm.x; mk[u][1] = mm.y; mk[u][2] = mm.z; mk[u][3] = mm.w;
                }
                vl[u][0] = vl[u][1] = vl[u][2] = vl[u][3] = 1;
            } else {
                for (int j = 0; j < 4; ++j) {
                    int n = tn * 4 + j;
                    vl[u][j] = (n < nvalid);
                    if (vl[u][j]) {
                        xv[u][j] = p.x[base + j]; tv4[j] = p.t[base + j];
                        mk[u][j] = (mode == 1) ? (int)m8[base + j]
                                 : (mode == 2) ? (mf[base + j] != 0.f) : m32[base + j];
                    } else { xv[u][j] = 0.f; tv4[j] = 0.f; mk[u][j] = 0; }
                }
            }
#pragma unroll
            for (int j = 0; j < 4; ++j) {
                float pq = tv4[j] * (float)KTAB;
                pq = fminf(fmaxf(pq, 0.f), (float)KTAB - 0.001f);
                int ii = (int)pq;
                fr[u][j] = pq - (float)ii;
                off[u][j] = (unsigned)((b * FSTRIDE + ii) << 2);
                float g0 = p.gtab[ii];
                gv[u][j] = g0 + (p.gtab[ii + 1] - g0) * fr[u][j];
            }
        }
        float fa[2][4], fb[2][4];
        ld_ft16(p.ftab,
                off[0][0], off[0][1], off[0][2], off[0][3],
                off[1][0], off[1][1], off[1][2], off[1][3],
                fa[0][0], fb[0][0], fa[0][1], fb[0][1], fa[0][2], fb[0][2], fa[0][3], fb[0][3],
                fa[1][0], fb[1][0], fa[1][1], fb[1][1], fa[1][2], fb[1][2], fa[1][3], fb[1][3]);
#pragma unroll
        for (int u = 0; u < 2; ++u) {
            int i = ih * 2 + u, b = tb * 4 + i;
#pragma unroll
            for (int j = 0; j < 4; ++j) {
                if (!vl[u][j]) continue;
                float fv = fa[u][j] + (fb[u][j] - fa[u][j]) * fr[u][j];
                float sc2 = SCALE * (xv[u][j] * u0_s[b] + acc[i][j] + fv + qbk_s[b]);
                if (mk[u][j] == 0) sc2 = NEG1E9;
                float val = xv[u][j] * c0 + memv_s[tn * 4 + j] + gv[u][j];
                if (sc2 > pm[i]) {
                    float a = __expf(pm[i] - sc2);
                    pd[i] = pd[i] * a + 1.f;
                    pn[i] = pn[i] * a + val;
                    pm[i] = sc2;
                } else {
                    float e = __expf(sc2 - pm[i]);
                    pd[i] += e;
                    pn[i] += e * val;
                }
            }
        }
    }
#pragma unroll
    for (int mk2 = 1; mk2 < 16; mk2 <<= 1) {
#pragma unroll
        for (int i = 0; i < 4; ++i) {
            float mo = __shfl_xor(pm[i], mk2);
            float d2 = __shfl_xor(pd[i], mk2);
            float n2 = __shfl_xor(pn[i], mk2);
            float M = fmaxf(pm[i], mo);
            float e1 = __expf(pm[i] - M), e2 = __expf(mo - M);
            pd[i] = pd[i] * e1 + d2 * e2;
            pn[i] = pn[i] * e1 + n2 * e2;
            pm[i] = M;
        }
    }
    if (tn == 0) {
#pragma unroll
        for (int i = 0; i < 4; ++i) {
            int b = tb * 4 + i;
            st_f4(p.partials, (b * NTILES + tile) * 4, (v4f){pm[i], pd[i], pn[i], 0.f});
        }
    }
}

__global__ __launch_bounds__(256, 2) void fused_kernel(KParams p) {
    __shared__ __align__(16) float sm[9280];
    int blk = blockIdx.x, tid = threadIdx.x;
    int grp = blk / GW;
    unsigned gsz = (grp == GRPS - 1) ? (unsigned)(NBLK - (GRPS - 1) * GW) : (unsigned)GW;
    unsigned kbar = 0;

    // ---- P0: zero mem (sc) + transposes + costab + wv_out/vconst/qconst + mode detect ----
    {
        int gtid = blk * 256 + tid;
        v4f z4 = (v4f){0.f, 0.f, 0.f, 0.f};
        for (int i = gtid; i < (NN * LAT) / 4; i += NBLK * 256) st_f4(p.mem, i * 4, z4);
        if (blk < 256) {
            const int GS = 256 * 256;
            for (int i = gtid; i < 129 * 384; i += GS) {
                int d = i / 384, j = i % 384;
                st_f1(p.W_ihT, i, p.W_ih[j * 129 + d]);
            }
            for (int i = gtid; i < 128 * 384; i += GS) {
                int l = i / 384, j = i % 384;
                st_f1(p.W_hhT, i, p.W_hh[j * 128 + l]);
            }
            for (int pp = gtid; pp <= KTAB; pp += GS) {
                float tv = (float)pp * (1.0f / KTAB);
                for (int l = 0; l < 128; ++l)
                    st_f1(p.costab, l * CSTRIDE + pp, __cosf(tv * p.tw[l] + p.tb_[l]));
            }
        } else if (blk == 256) {
            for (int d = tid; d < DH; d += 256) {
                float a = 0.f;
                for (int j = 0; j < LAT; ++j) a += p.Wv[d * LAT + j] * p.W_out[j];
                st_f1(p.wv_out, d, a);
            }
            if (tid == 0) {
                float a = p.b_out[0];
                for (int j = 0; j < LAT; ++j) a += p.bv[j] * p.W_out[j];
                st_f1(p.vconst, 0, a);
            }
            if (tid < 128) {
                float a = p.bq[tid];
                for (int j = 0; j < 128; ++j) a += __cosf(p.tb_[j]) * p.Wq[(129 + j) * LAT + tid];
                st_f1(p.qconst, tid, a);
            }
            int* smi = (int*)sm;
            if (tid == 0) { smi[0] = 0; smi[1] = 0; }
            __syncthreads();
            const int* mask = (const int*)p.maskp;
            for (int i = tid; i < 4096; i += 256) {
                int v = mask[i];
                if ((unsigned)v > 1u) atomicOr(&smi[0], 1);
                if (v == 0x3F800000) atomicOr(&smi[1], 1);
            }
            __syncthreads();
            if (tid == 0)
                st_f1((float*)p.modep, 0, __int_as_float(smi[1] ? 2 : (smi[0] ? 1 : 0)));
        }
    }
    kbar += 1; gbar_fast(p.barcnt, grp, gsz, kbar);

    // ---- P1: setup2 (131) + gtab (5) + GRU s=0 (128) ----
    {
        if (blk < 131) {
            float* vrow = sm;   // 128
            if (blk < 128) {    // BT row l
                int l = blk;
                if (tid < 128) vrow[tid] = p.Wq[(1 + l) * LAT + tid];
                __syncthreads();
                for (int d = tid; d < DH; d += 256) {
                    const float* wkr = p.Wk + d * LAT;
                    float a = 0.f;
#pragma unroll 4
                    for (int j = 0; j < 128; ++j) a += wkr[j] * vrow[j];
                    st_f1(p.BT, l * 260 + d, a);
                }
            } else if (blk == 128) {    // uc = Wk @ qconst
                if (tid < 128) vrow[tid] = ld_f1(p.qconst, tid);
                __syncthreads();
                for (int d = tid; d < DH; d += 256) {
                    const float* wkr = p.Wk + d * LAT;
                    float a = 0.f;
#pragma unroll 4
                    for (int j = 0; j < 128; ++j) a += wkr[j] * vrow[j];
                    st_f1(p.uc, d, a);
                }
            } else if (blk == 129) {    // kw0 = Wk @ Wq[0,:]
                if (tid < 128) vrow[tid] = p.Wq[tid];
                __syncthreads();
                for (int d = tid; d < DH; d += 256) {
                    const float* wkr = p.Wk + d * LAT;
                    float a = 0.f;
#pragma unroll 4
                    for (int j = 0; j < 128; ++j) a += wkr[j] * vrow[j];
                    st_f1(p.kw0, d, a);
                }
            } else {                    // abk + scal
                if (tid < 128) vrow[tid] = p.bk[tid];
                __syncthreads();
                if (tid < 128) {
                    const float* wqr = p.Wq + (1 + tid) * LAT;
                    float a = 0.f;
#pragma unroll 4
                    for (int j = 0; j < 128; ++j) a += wqr[j] * vrow[j];
                    st_f1(p.abk, tid, a);
                } else if (tid == 128) {
                    float a = 0.f;
                    for (int j = 0; j < 128; ++j) a += ld_f1(p.qconst, j) * p.bk[j];
                    st_f1(p.scal, 0, a);
                } else if (tid == 129) {
                    float a = 0.f;
                    for (int j = 0; j < 128; ++j) a += p.Wq[j] * p.bk[j];
                    st_f1(p.scal, 1, a);
                }
            }
        } else if (blk < 136) {     // gtab (reads costab sc-fresh via MALL, wv_out sc)
            float* wv_s = sm;
            if (tid < LAT) wv_s[tid] = ld_f1(p.wv_out, 129 + tid);
            __syncthreads();
            int pp = (blk - 131) * 256 + tid;
            if (pp <= KTAB) {
                float a = 0.f;
                for (int l = 0; l < 128; ++l) a += wv_s[l] * ld_f1(p.costab, l * CSTRIDE + pp);
                st_f1(p.gtab, pp, a);
            }
        } else if (blk < 264) {     // GRU rows for s=0 (h = 0)
            do_gru_sc(blk - 136, tid, 0, 1, p, sm);
        }
    }
    kbar += 1; gbar_fast(p.barcnt, grp, gsz, kbar);

    // ---- main loop: A-phase | bar | B-phase | bar ----
    for (int s = 0; s < S_LEN; ++s) {
        if (blk < 64) {
            a_work256(p, sm, blk, s);
        } else if (blk == 64) {
            scatter256(p, sm, s);
        } else if (blk >= 66 && blk < 130) {
            if (s > 0) combine_block(p, blk - 66, s - 1, sm);
        }
        kbar += 1; gbar_fast(p.barcnt, grp, gsz, kbar);
        if (blk < NTILES) {
            attn_tile256(p, sm, blk, s);
        } else {
            if (s < S_LEN - 1) do_gru_sc(blk - NTILES, tid, s + 1, 0, p, sm);
        }
        kbar += 1; gbar_fast(p.barcnt, grp, gsz, kbar);
    }
    if (blk >= 66 && blk < 130) combine_block(p, blk - 66, S_LEN - 1, sm);
}

// ============================================================================================
// Fallback: verified multi-kernel path (round-0), used only if cooperative launch fails.
// ============================================================================================
__device__ __forceinline__ void do_gru_row256(int r, int tid2, int s, int zeroH,
    const float* __restrict__ x, const float* __restrict__ t,
    const int* __restrict__ source, const int* __restrict__ target,
    const float* __restrict__ tw, const float* __restrict__ tb_,
    const float* __restrict__ W_ihT, const float* __restrict__ W_hhT,
    const float* __restrict__ b_ih, const float* __restrict__ b_hh,
    const float* __restrict__ mem, float* __restrict__ newh, float* sm) {
    float* msg = sm;
    float* h   = sm + 132;
    float* gi3 = sm + 260;
    float* gh3 = sm + 644;
    int b = r & 63;
    int idx = (r < 64) ? source[s * BSZ + b] : target[s * BSZ + b];
    const float* xs = x + (size_t)(s * BSZ + b) * NN;
    const float* ts = t + (size_t)(s * BSZ + b) * NN;
    if (tid2 == 0) msg[0] = xs[idx];
    if (tid2 < 128) {
        float tv = ts[idx];
        msg[1 + tid2] = __cosf(tv * tw[tid2] + tb_[tid2]);
        h[tid2] = zeroH ? 0.f : mem[(size_t)idx * LAT + tid2];
    }
    __syncthreads();
    if (tid2 < 128) {
        int j = tid2;
        float a0 = b_ih[j], a1 = b_ih[128 + j], a2 = b_ih[256 + j];
#pragma unroll 4
        for (int d = 0; d < 129; ++d) {
            float m = msg[d];
            const float* col = W_ihT + d * 384;
            a0 += m * col[j]; a1 += m * col[128 + j]; a2 += m * col[256 + j];
        }
        gi3[j] = a0; gi3[128 + j] = a1; gi3[256 + j] = a2;
    } else {
        int j = tid2 - 128;
        float a0 = b_hh[j], a1 = b_hh[128 + j], a2 = b_hh[256 + j];
#pragma unroll 4
        for (int l = 0; l < 128; ++l) {
            float hv = h[l];
            const float* col = W_hhT + l * 384;
            a0 += hv * col[j]; a1 += hv * col[128 + j]; a2 += hv * col[256 + j];
        }
        gh3[j] = a0; gh3[128 + j] = a1; gh3[256 + j] = a2;
    }
    __syncthreads();
    if (tid2 < 128) {
        int j = tid2;
        float rr = 1.f / (1.f + __expf(-(gi3[j] + gh3[j])));
        float zz = 1.f / (1.f + __expf(-(gi3[128 + j] + gh3[128 + j])));
        float nn2 = tanhf(gi3[256 + j] + rr * gh3[256 + j]);
        newh[r * LAT + j] = (1.f - zz) * nn2 + zz * h[j];
    }
}

__device__ __forceinline__ void do_combine(const float* __restrict__ partials,
                                           const float* __restrict__ vconst,
                                           float* __restrict__ out, int ps, int tid) {
    if (tid >= 64) return;
    int b = tid;
    float M = -3.0e38f, D = 0.f, Nm = 0.f;
    const float4* pp = (const float4*)partials + b * NTILES;
    for (int i = 0; i < NTILES; ++i) {
        float4 p = pp[i];
        float M2 = fmaxf(M, p.x);
        float e1 = __expf(M - M2), e2 = __expf(p.x - M2);
        D = D * e1 + p.y * e2;
        Nm = Nm * e1 + p.z * e2;
        M = M2;
    }
    out[ps * BSZ + b] = Nm / D + vconst[0];
}

__global__ __launch_bounds__(256) void setup_all_kernel(
    const float* __restrict__ W_ih, const float* __restrict__ W_hh,
    const float* __restrict__ tw, const float* __restrict__ tb_,
    const float* __restrict__ Wq, const float* __restrict__ bq,
    const float* __restrict__ Wv, const float* __restrict__ bv,
    const float* __restrict__ W_out, const float* __restrict__ b_out,
    const int* __restrict__ mask,
    float* __restrict__ W_ihT, float* __restrict__ W_hhT,
    float* __restrict__ costab, float* __restrict__ wv_out, float* __restrict__ vconst,
    float* __restrict__ qconst, int* __restrict__ modep) {
    int blk = blockIdx.x, tid = threadIdx.x;
    if (blk < 256) {
        int gtid = blk * 256 + tid;
        const int GS = 256 * 256;
        for (int i = gtid; i < 129 * 384; i += GS) { int d = i / 384, j = i % 384; W_ihT[i] = W_ih[j * 129 + d]; }
        for (int i = gtid; i < 128 * 384; i += GS) { int l = i / 384, j = i % 384; W_hhT[i] = W_hh[j * 128 + l]; }
        for (int p = gtid; p <= KTAB; p += GS) {
            float tv = (float)p * (1.0f / KTAB);
            for (int l = 0; l < 128; ++l) costab[l * CSTRIDE + p] = __cosf(tv * tw[l] + tb_[l]);
        }
    } else {
        for (int d = tid; d < DH; d += 256) {
            float a = 0.f;
            for (int j = 0; j < LAT; ++j) a += Wv[d * LAT + j] * W_out[j];
            wv_out[d] = a;
        }
        if (tid == 0) {
            float a = b_out[0];
            for (int j = 0; j < LAT; ++j) a += bv[j] * W_out[j];
            *vconst = a;
        }
        if (tid < 128) {
            float a = bq[tid];
            for (int j = 0; j < 128; ++j) a += __cosf(tb_[j]) * Wq[(129 + j) * LAT + tid];
            qconst[tid] = a;
        }
        __shared__ int hasHigh, hasFloat;
        if (tid == 0) { hasHigh = 0; hasFloat = 0; }
        __syncthreads();
        for (int i = tid; i < 4096; i += 256) {
            int v = mask[i];
            if ((unsigned)v > 1u) atomicOr(&hasHigh, 1);
            if (v == 0x3F800000) atomicOr(&hasFloat, 1);
        }
        __syncthreads();
        if (tid == 0) *modep = hasFloat ? 2 : (hasHigh ? 1 : 0);
    }
}

__global__ __launch_bounds__(256) void setup2_kernel(
    const float* __restrict__ Wk, const float* __restrict__ Wq,
    const float* __restrict__ bk, const float* __restrict__ qconst,
    float* __restrict__ BT, float* __restrict__ uc, float* __restrict__ kw0,
    float* __restrict__ abk, float* __restrict__ scal) {
    int blk = blockIdx.x, tid = threadIdx.x;
    __shared__ float vrow[128];
    if (blk < 128) {
        int l = blk;
        if (tid < 128) vrow[tid] = Wq[(1 + l) * LAT + tid];
        __syncthreads();
        for (int d = tid; d < DH; d += 256) {
            const float* wkr = Wk + d * LAT;
            float a = 0.f;
#pragma unroll 4
            for (int j = 0; j < 128; ++j) a += wkr[j] * vrow[j];
            BT[l * 260 + d] = a;
        }
    } else if (blk == 128) {
        if (tid < 128) vrow[tid] = qconst[tid];
        __syncthreads();
        for (int d = tid; d < DH; d += 256) {
            const float* wkr = Wk + d * LAT;
            float a = 0.f;
#pragma unroll 4
            for (int j = 0; j < 128; ++j) a += wkr[j] * vrow[j];
            uc[d] = a;
        }
    } else if (blk == 129) {
        if (tid < 128) vrow[tid] = Wq[tid];
        __syncthreads();
        for (int d = tid; d < DH; d += 256) {
            const float* wkr = Wk + d * LAT;
            float a = 0.f;
#pragma unroll 4
            for (int j = 0; j < 128; ++j) a += wkr[j] * vrow[j];
            kw0[d] = a;
        }
    } else {
        if (tid < 128) vrow[tid] = bk[tid];
        __syncthreads();
        if (tid < 128) {
            const float* wqr = Wq + (1 + tid) * LAT;
            float a = 0.f;
#pragma unroll 4
            for (int j = 0; j < 128; ++j) a += wqr[j] * vrow[j];
            abk[tid] = a;
        } else if (tid == 128) {
            float a = 0.f;
            for (int j = 0; j < 128; ++j) a += qconst[j] * bk[j];
            scal[0] = a;
        } else if (tid == 129) {
            float a = 0.f;
            for (int j = 0; j < 128; ++j) a += Wq[j] * bk[j];
            scal[1] = a;
        }
    }
}

__global__ __launch_bounds__(256) void pre_kernel(
    const float* __restrict__ x, const float* __restrict__ t,
    const int* __restrict__ source, const int* __restrict__ target,
    const float* __restrict__ tw, const float* __restrict__ tb_,
    const float* __restrict__ W_ihT, const float* __restrict__ W_hhT,
    const float* __restrict__ b_ih, const float* __restrict__ b_hh,
    const float* __restrict__ mem, float* __restrict__ newh,
    const float* __restrict__ wv_out, const float* __restrict__ costab,
    float* __restrict__ gtab) {
    __shared__ __align__(16) float sm[1028];
    int blk = blockIdx.x, tid = threadIdx.x;
    if (blk < 5) {
        __shared__ float wv_s[LAT];
        if (tid < LAT) wv_s[tid] = wv_out[129 + tid];
        __syncthreads();
        int p = blk * 256 + tid;
        if (p <= KTAB) {
            float a = 0.f;
            for (int l = 0; l < 128; ++l) a += wv_s[l] * costab[l * CSTRIDE + p];
            gtab[p] = a;
        }
        return;
    }
    int r = blk - 5;
    do_gru_row256(r, tid, 0, 0, x, t, source, target, tw, tb_,
                  W_ihT, W_hhT, b_ih, b_hh, mem, newh, sm);
}

__global__ __launch_bounds__(512) void step_a3_kernel(
    const float* __restrict__ x, const int* __restrict__ source, const int* __restrict__ target,
    const float* __restrict__ BT, const float* __restrict__ uc, const float* __restrict__ kw0,
    const float* __restrict__ abk, const float* __restrict__ scal,
    const float* __restrict__ newh, float* __restrict__ mem,
    float* __restrict__ u0_g, float* __restrict__ qbk_g, float* __restrict__ uT,
    float* __restrict__ ftab, const float* __restrict__ costab,
    const float* __restrict__ partials, const float* __restrict__ vconst,
    float* __restrict__ out, int s) {
    int blk = blockIdx.x;
    int tid = threadIdx.x;
    if (blk == 64) {
        __shared__ int idxs[128];
        __shared__ int alive[128];
        if (tid < 128) idxs[tid] = (tid < 64) ? source[s * BSZ + tid] : target[s * BSZ + (tid - 64)];
        __syncthreads();
        if (tid < 128) {
            int i2 = idxs[tid];
            int a = 1;
            for (int r2 = tid + 1; r2 < 128; ++r2)
                if (idxs[r2] == i2) { a = 0; break; }
            alive[tid] = a;
        }
        __syncthreads();
        int row = tid >> 2, q4 = tid & 3;
        if (alive[row]) {
            const float4* srcp = (const float4*)(newh + row * LAT + q4 * 32);
            float4* dstp = (float4*)(mem + (size_t)idxs[row] * LAT + q4 * 32);
#pragma unroll
            for (int j = 0; j < 8; ++j) dstp[j] = srcp[j];
        }
        return;
    }
    if (blk == 65) {
        if (s > 0) do_combine(partials, vconst, out, s - 1, tid);
        return;
    }
    int b = blk;
    __shared__ float memv[128];
    __shared__ float udt_s[128];
    __shared__ float upart[4][260];
    __shared__ float red[8];
    __shared__ __align__(16) float fpart[3 * 1024];
    __shared__ int s_last;
    __shared__ float xvs;
    if (tid < 64) {
        unsigned long long mball = __ballot(target[s * BSZ + tid] == target[s * BSZ + b]);
        if (tid == 0) {
            s_last = 63 - __builtin_clzll(mball);
            xvs = x[(size_t)(s * BSZ + b) * NN + target[s * BSZ + b]];
        }
    }
    __syncthreads();
    if (tid < 128) memv[tid] = newh[(64 + s_last) * LAT + tid];
    __syncthreads();
    float xv = xvs;
    {
        int dd = tid & 127, kc = tid >> 7;
        int l0 = kc * 32;
        for (int d = dd; d < DH; d += 128) {
            float a = 0.f;
#pragma unroll 4
            for (int l = l0; l < l0 + 32; ++l) a += memv[l] * BT[l * 260 + d];
            upart[kc][d] = a;
        }
    }
    __syncthreads();
    if (tid < 257) {
        float a = uc[tid] + xv * kw0[tid] + upart[0][tid] + upart[1][tid] + upart[2][tid] + upart[3][tid];
        if (tid == 0) u0_g[b] = a;
        else if (tid <= 128) uT[(tid - 1) * BSZ + b] = a;
        else udt_s[tid - 129] = a;
    }
    if (tid >= 448) {
        int i = tid - 448;
        float a = memv[i] * abk[i] + memv[64 + i] * abk[64 + i];
        for (int off = 32; off; off >>= 1) a += __shfl_down(a, off, 64);
        if (i == 0) qbk_g[b] = scal[0] + xv * scal[1] + a;
    }
    __syncthreads();
    {
        int pi = tid & 127, lc = tid >> 7;
        int l0 = lc * 32;
        float a0x = 0.f, a0y = 0.f, a0z = 0.f, a0w = 0.f;
        float a1x = 0.f, a1y = 0.f, a1z = 0.f, a1w = 0.f;
#pragma unroll 4
        for (int l = l0; l < l0 + 32; ++l) {
            float ul = udt_s[l];
            const float* cp = &costab[l * CSTRIDE + pi * 8];
            float4 c0 = *(const float4*)cp;
            float4 c1 = *(const float4*)(cp + 4);
            a0x += ul * c0.x; a0y += ul * c0.y; a0z += ul * c0.z; a0w += ul * c0.w;
            a1x += ul * c1.x; a1y += ul * c1.y; a1z += ul * c1.z; a1w += ul * c1.w;
        }
        if (lc) {
            float* fp = &fpart[(lc - 1) * 1024 + pi * 8];
            *(float4*)fp = make_float4(a0x, a0y, a0z, a0w);
            *(float4*)(fp + 4) = make_float4(a1x, a1y, a1z, a1w);
        }
        if (pi == 127) {
            float a = 0.f;
            for (int l = l0; l < l0 + 32; ++l) a += udt_s[l] * costab[l * CSTRIDE + KTAB];
            red[lc] = a;
        }
        __syncthreads();
        if (lc == 0) {
            for (int c = 0; c < 3; ++c) {
                const float* fp = &fpart[c * 1024 + pi * 8];
                a0x += fp[0]; a0y += fp[1]; a0z += fp[2]; a0w += fp[3];
                a1x += fp[4]; a1y += fp[5]; a1z += fp[6]; a1w += fp[7];
            }
            float* fo = &ftab[b * FSTRIDE + pi * 8];
            *(float4*)fo = make_float4(a0x, a0y, a0z, a0w);
            *(float4*)(fo + 4) = make_float4(a1x, a1y, a1z, a1w);
        }
        if (tid == 0) ftab[b * FSTRIDE + KTAB] = red[0] + red[1] + red[2] + red[3];
    }
}

__global__ __launch_bounds__(256) void step_b2_kernel(
    const float* __restrict__ x, const float* __restrict__ t,
    const void* __restrict__ maskp, const int* __restrict__ modep,
    const int* __restrict__ source, const int* __restrict__ target,
    const float* __restrict__ tw, const float* __restrict__ tb_,
    const float* __restrict__ W_ihT, const float* __restrict__ W_hhT,
    const float* __restrict__ b_ih, const float* __restrict__ b_hh,
    const float* __restrict__ mem, float* __restrict__ newh,
    const float* __restrict__ uT, const float* __restrict__ u0_g,
    const float* __restrict__ qbk_g, const float* __restrict__ ftab,
    const float* __restrict__ gtab, const float* __restrict__ wv_out,
    float* __restrict__ partials, int s) {
    int blk = blockIdx.x, tid = threadIdx.x;
    __shared__ __align__(16) float sm[9280];
    if (blk >= NTILES) {
        if (s < S_LEN - 1) {
            int r = blk - NTILES;
            do_gru_row256(r, tid, s + 1, 0, x, t, source, target, tw, tb_,
                          W_ihT, W_hhT, b_ih, b_hh, mem, newh, sm);
        }
        return;
    }
    float* memT   = sm;
    float* uTs    = sm + 4608;
    float* memv_s = sm + 8960;
    float* wv_s   = sm + 9024;
    float* u0_s   = sm + 9152;
    float* qbk_s  = sm + 9216;
    int tile = blk;
    int n0 = tile * NTILE;
    int tb = tid >> 4, tn = tid & 15;
    int nvalid = NN - n0; if (nvalid > NTILE) nvalid = NTILE;

    if (tid < 128) wv_s[tid] = wv_out[1 + tid];
    if (tid < 64) { u0_s[tid] = u0_g[tid]; qbk_s[tid] = qbk_g[tid]; memv_s[tid] = 0.f; }

    float acc[4][4];
#pragma unroll
    for (int i = 0; i < 4; ++i)
#pragma unroll
        for (int j = 0; j < 4; ++j) acc[i][j] = 0.f;

    for (int l0 = 0; l0 < 128; l0 += 64) {
        __syncthreads();
        {
            int n_l = tid & 63, lq = (tid >> 6) * 16;
            if (n_l < nvalid) {
                const float* mrow = mem + (size_t)(n0 + n_l) * LAT + l0 + lq;
                float4 a0 = *(const float4*)(mrow + 0);
                float4 a1 = *(const float4*)(mrow + 4);
                float4 a2 = *(const float4*)(mrow + 8);
                float4 a3 = *(const float4*)(mrow + 12);
                memT[(lq + 0) * 72 + n_l] = a0.x; memT[(lq + 1) * 72 + n_l] = a0.y;
                memT[(lq + 2) * 72 + n_l] = a0.z; memT[(lq + 3) * 72 + n_l] = a0.w;
                memT[(lq + 4) * 72 + n_l] = a1.x; memT[(lq + 5) * 72 + n_l] = a1.y;
                memT[(lq + 6) * 72 + n_l] = a1.z; memT[(lq + 7) * 72 + n_l] = a1.w;
                memT[(lq + 8) * 72 + n_l] = a2.x; memT[(lq + 9) * 72 + n_l] = a2.y;
                memT[(lq + 10) * 72 + n_l] = a2.z; memT[(lq + 11) * 72 + n_l] = a2.w;
                memT[(lq + 12) * 72 + n_l] = a3.x; memT[(lq + 13) * 72 + n_l] = a3.y;
                memT[(lq + 14) * 72 + n_l] = a3.z; memT[(lq + 15) * 72 + n_l] = a3.w;
            } else {
                for (int j = 0; j < 16; ++j) memT[(lq + j) * 72 + n_l] = 0.f;
            }
        }
        {
            int bq4 = (tid & 15) * 4;
            int ll = (tid >> 4) * 4;
            for (int j = 0; j < 4; ++j) {
                float4 v = *(const float4*)&uT[(l0 + ll + j) * BSZ + bq4];
                *(float4*)&uTs[(ll + j) * 68 + bq4] = v;
            }
        }
        __syncthreads();
        if (tid < 64) {
            float a = memv_s[tid];
            for (int l = 0; l < 64; ++l) a += wv_s[l0 + l] * memT[l * 72 + tid];
            memv_s[tid] = a;
        }
        for (int l = 0; l < 64; ++l) {
            float4 uv = *(const float4*)&uTs[l * 68 + tb * 4];
            float4 mv = *(const float4*)&memT[l * 72 + tn * 4];
            acc[0][0] += uv.x * mv.x; acc[0][1] += uv.x * mv.y; acc[0][2] += uv.x * mv.z; acc[0][3] += uv.x * mv.w;
            acc[1][0] += uv.y * mv.x; acc[1][1] += uv.y * mv.y; acc[1][2] += uv.y * mv.z; acc[1][3] += uv.y * mv.w;
            acc[2][0] += uv.z * mv.x; acc[2][1] += uv.z * mv.y; acc[2][2] += uv.z * mv.z; acc[2][3] += uv.z * mv.w;
            acc[3][0] += uv.w * mv.x; acc[3][1] += uv.w * mv.y; acc[3][2] += uv.w * mv.z; acc[3][3] += uv.w * mv.w;
        }
    }
    __syncthreads();

    const float c0 = wv_out[0];
    int mode = *modep;
    const int* m32 = (const int*)maskp;
    const unsigned char* m8 = (const unsigned char*)maskp;
    const float* mf = (const float*)maskp;

    float pm[4], pd[4], pn[4];
#pragma unroll
    for (int i = 0; i < 4; ++i) { pm[i] = -3.0e38f; pd[i] = 0.f; pn[i] = 0.f; }

    for (int i = 0; i < 4; ++i) {
        int b = tb * 4 + i;
        size_t base = (size_t)(s * BSZ + b) * NN + n0 + tn * 4;
        float xv4[4], tv4[4]; int msk[4], vld[4];
        if (tn * 4 + 3 < nvalid) {
            float4 xx = *(const float4*)(x + base);
            float4 tt = *(const float4*)(t + base);
            xv4[0] = xx.x; xv4[1] = xx.y; xv4[2] = xx.z; xv4[3] = xx.w;
            tv4[0] = tt.x; tv4[1] = tt.y; tv4[2] = tt.z; tv4[3] = tt.w;
            if (mode == 1) {
                unsigned mw = *(const unsigned*)(m8 + base);
                msk[0] = mw & 0xff; msk[1] = (mw >> 8) & 0xff; msk[2] = (mw >> 16) & 0xff; msk[3] = (mw >> 24) & 0xff;
            } else if (mode == 2) {
                float4 mm = *(const float4*)(mf + base);
                msk[0] = (mm.x != 0.f); msk[1] = (mm.y != 0.f); msk[2] = (mm.z != 0.f); msk[3] = (mm.w != 0.f);
            } else {
                int4 mm = *(const int4*)(m32 + base);
                msk[0] = mm.x; msk[1] = mm.y; msk[2] = mm.z; msk[3] = mm.w;
            }
            vld[0] = vld[1] = vld[2] = vld[3] = 1;
        } else {
            for (int j = 0; j < 4; ++j) {
                int n = tn * 4 + j;
                vld[j] = (n < nvalid);
                if (vld[j]) {
                    xv4[j] = x[base + j]; tv4[j] = t[base + j];
                    msk[j] = (mode == 1) ? (int)m8[base + j] : (mode == 2) ? (mf[base + j] != 0.f) : m32[base + j];
                } else { xv4[j] = 0.f; tv4[j] = 0.f; msk[j] = 0; }
            }
        }
        const float* ft = ftab + b * FSTRIDE;
#pragma unroll
        for (int j = 0; j < 4; ++j) {
            if (!vld[j]) continue;
            float xv = xv4[j], tv = tv4[j];
            float pq = tv * (float)KTAB;
            pq = fminf(fmaxf(pq, 0.f), (float)KTAB - 0.001f);
            int ii = (int)pq;
            float fr = pq - (float)ii;
            float f0 = ft[ii];
            float fv = f0 + (ft[ii + 1] - f0) * fr;
            float g0 = gtab[ii];
            float gv = g0 + (gtab[ii + 1] - g0) * fr;
            float sc = SCALE * (xv * u0_s[b] + acc[i][j] + fv + qbk_s[b]);
            if (msk[j] == 0) sc = NEG1E9;
            float val = xv * c0 + memv_s[tn * 4 + j] + gv;
            if (sc > pm[i]) {
                float a = __expf(pm[i] - sc);
                pd[i] = pd[i] * a + 1.f;
                pn[i] = pn[i] * a + val;
                pm[i] = sc;
            } else {
                float e = __expf(sc - pm[i]);
                pd[i] += e;
                pn[i] += e * val;
            }
        }
    }
#pragma unroll
    for (int mk2 = 1; mk2 < 16; mk2 <<= 1) {
#pragma unroll
        for (int i = 0; i < 4; ++i) {
            float mo = __shfl_xor(pm[i], mk2);
            float d2 = __shfl_xor(pd[i], mk2);
            float n2 = __shfl_xor(pn[i], mk2);
            float M = fmaxf(pm[i], mo);
            float e1 = __expf(pm[i] - M), e2 = __expf(mo - M);
            pd[i] = pd[i] * e1 + d2 * e2;
            pn[i] = pn[i] * e1 + n2 * e2;
            pm[i] = M;
        }
    }
    if (tn == 0) {
#pragma unroll
        for (int i = 0; i < 4; ++i) {
            int b = tb * 4 + i;
            *(float4*)&partials[(size_t)(b * NTILES + tile) * 4] = make_float4(pm[i], pd[i], pn[i], 0.f);
        }
    }
}

__global__ __launch_bounds__(64) void tail_kernel(const float* __restrict__ partials,
                                                  const float* __restrict__ vconst,
                                                  float* __restrict__ out) {
    do_combine(partials, vconst, out, S_LEN - 1, threadIdx.x);
}

extern "C" void kernel_launch(void* const* d_in, const int* in_sizes, int n_in,
                              void* d_out, int out_size, void* d_ws, size_t ws_size,
                              hipStream_t stream) {
    const float* x      = (const float*)d_in[0];
    const float* t      = (const float*)d_in[1];
    const int*   source = (const int*)d_in[2];
    const int*   target = (const int*)d_in[3];
    const void*  maskp  = (const void*)d_in[4];
    const float* tw     = (const float*)d_in[5];
    const float* tb     = (const float*)d_in[6];
    const float* W_ih   = (const float*)d_in[7];
    const float* W_hh   = (const float*)d_in[8];
    const float* b_ih   = (const float*)d_in[9];
    const float* b_hh   = (const float*)d_in[10];
    const float* Wq     = (const float*)d_in[11];
    const float* bq     = (const float*)d_in[12];
    const float* Wk     = (const float*)d_in[13];
    const float* bk     = (const float*)d_in[14];
    const float* Wv     = (const float*)d_in[15];
    const float* bv     = (const float*)d_in[16];
    const float* W_out  = (const float*)d_in[17];
    const float* b_out  = (const float*)d_in[18];
    float* out = (float*)d_out;

    // All regions padded to 32-float (128B cacheline) multiples so no line mixes
    // cached-read data with sc-written data.
    float* w = (float*)d_ws;
    float* mem    = w; w += (size_t)NN * LAT;        // 1,280,000
    float* newh   = w; w += 128 * LAT;               // 16,384
    float* uT     = w; w += LAT * BSZ;               // 8,192
    float* u0_g   = w; w += BSZ;                     // 64  (qbk_g MUST follow: attn ld_2)
    float* qbk_g  = w; w += BSZ;                     // 64
    float* ftab   = w; w += BSZ * FSTRIDE;           // 65,792
    float* gtab   = w; w += 1056;                    // 1025 used, padded
    float* costab = w; w += LAT * CSTRIDE;           // 132,096
    float* partials = w; w += (size_t)BSZ * NTILES * 4; // 40,192
    float* wv_out = w; w += 288;                     // 257 used, padded
    float* vconst = w; w += 32;
    float* W_ihT  = w; w += 129 * 384;               // 49,536
    float* W_hhT  = w; w += 128 * 384;               // 49,152
    float* BT     = w; w += 128 * 260;               // 33,280
    float* uc     = w; w += 288;                     // 257 used, padded
    float* kw0    = w; w += 288;
    float* abk    = w; w += 128;
    float* qconst = w; w += 128;
    float* scal   = w; w += 32;
    int*   modep  = (int*)w; w += 32;
    unsigned* barcnt = (unsigned*)w; w += (GRPS * 2 + 1) * 64;   // 33 x 256B slots

    KParams kp;
    kp.x = x; kp.t = t; kp.source = source; kp.target = target; kp.maskp = maskp;
    kp.tw = tw; kp.tb_ = tb;
    kp.W_ih = W_ih; kp.W_hh = W_hh; kp.b_ih = b_ih; kp.b_hh = b_hh;
    kp.Wq = Wq; kp.bq = bq; kp.Wk = Wk; kp.bk = bk; kp.Wv = Wv; kp.bv = bv;
    kp.W_out = W_out; kp.b_out = b_out;
    kp.out = out;
    kp.mem = mem; kp.newh = newh; kp.uT = uT; kp.u0_g = u0_g; kp.qbk_g = qbk_g;
    kp.ftab = ftab; kp.gtab = gtab; kp.costab = costab; kp.partials = partials;
    kp.wv_out = wv_out; kp.vconst = vconst; kp.W_ihT = W_ihT; kp.W_hhT = W_hhT;
    kp.BT = BT; kp.uc = uc; kp.kw0 = kw0; kp.abk = abk; kp.qconst = qconst; kp.scal = scal;
    kp.modep = modep;
    kp.barcnt = barcnt;

    hipMemsetAsync(barcnt, 0, (GRPS * 2 + 1) * 64 * sizeof(unsigned), stream);

    void* args[] = { &kp };
    hipError_t err = hipLaunchCooperativeKernel((const void*)fused_kernel,
                                                dim3(NBLK), dim3(256), args, 0, stream);
    if (err != hipSuccess) {
        // Fallback: verified multi-kernel path.
        hipMemsetAsync(mem, 0, (size_t)NN * LAT * sizeof(float), stream);
        setup_all_kernel<<<257, 256, 0, stream>>>(W_ih, W_hh, tw, tb, Wq, bq, Wv, bv, W_out, b_out,
                                                  (const int*)maskp, W_ihT, W_hhT,
                                                  costab, wv_out, vconst, qconst, modep);
        setup2_kernel<<<131, 256, 0, stream>>>(Wk, Wq, bk, qconst, BT, uc, kw0, abk, scal);
        pre_kernel<<<133, 256, 0, stream>>>(x, t, source, target, tw, tb,
                                            W_ihT, W_hhT, b_ih, b_hh, mem, newh,
                                            wv_out, costab, gtab);
        for (int s = 0; s < S_LEN; ++s) {
            step_a3_kernel<<<66, 512, 0, stream>>>(x, source, target, BT, uc, kw0, abk, scal,
                                                   newh, mem, u0_g, qbk_g, uT, ftab, costab,
                                                   partials, vconst, out, s);
            step_b2_kernel<<<NTILES + 128, 256, 0, stream>>>(x, t, maskp, modep, source, target,
                                                             tw, tb, W_ihT, W_hhT, b_ih, b_hh,
                                                             mem, newh, uT, u0_g, qbk_g,
                                                             ftab, gtab, wv_out, partials, s);
        }
        tail_kernel<<<1, 64, 0, stream>>>(partials, vconst, out);
    }
}

// Round 5
// 832.172 us; speedup vs baseline: 3.2203x; 1.9710x over previous
//
#include <hip/hip_runtime.h>
#include <math.h>

#define S_LEN 16
#define BSZ   64
#define NN    10000
#define LAT   128
#define DH    257
#define KTAB  1024
#define CSTRIDE (KTAB + 8)    // costab leading dim
#define FSTRIDE (KTAB + 4)    // ftab leading dim
#define NTILE 64
#define NTILES 157            // ceil(10000/64)
#define STEP_BLKS 350         // 157 attn + 128 gru+A + 1 scatter + 64 combine
#define SCALE 0.08838834764831845f
#define NEG1E9 -1000000000.0f

struct KP {
    const float *x, *t;
    const int *source, *target;
    const void *maskp;
    const float *tw, *tb_;
    const float *W_ih, *W_hh, *b_ih, *b_hh;
    const float *Wq, *bq, *Wk, *bk, *Wv, *bv, *W_out, *b_out;
    float *out;
    float *mem;
    float *newh[2], *uT[2], *u0qbk[2], *ftab[2], *partials[2];
    float *gtab, *costab;
    float *wv_out, *vconst, *W_ihT, *W_hhT, *BT, *uc, *kw0, *abk, *scal;
    int *modep;
};

// ============================================================================================
// GRU row r for step snext (+ fold in A(snext) for the batch elems whose target last-writer
// is this row). Patch mem reads against step-sprev scatter set (scatter runs concurrently).
// sm: needs >= 2464 floats. Layout: msg[0..131] h[132..259] gi3[260..643] gh3[644..1027]
//     hn[1028..1155] itab(int)[1156..1283] axv[1284] amask[1288..1289] udt[1296..1423]
//     red2[1424..1425] fpart[1440..2463]
// ============================================================================================
__device__ void gru_a_block(const KP& p, float* sm, int r, int snext, int sprev, int zeroH) {
    int tid = threadIdx.x;
    int par = snext & 1;
    float* msg = sm;
    float* h   = sm + 132;
    float* gi3 = sm + 260;
    float* gh3 = sm + 644;
    float* hn  = sm + 1028;
    int*   itab = (int*)(sm + 1156);
    float* axv = sm + 1284;
    unsigned long long* amask = (unsigned long long*)(sm + 1288);
    float* udt = sm + 1296;
    float* red2 = sm + 1424;
    float* fpart = sm + 1440;

    int b = r & 63;
    int idx = (r < 64) ? p.source[snext * BSZ + b] : p.target[snext * BSZ + b];
    if (sprev >= 0 && tid < 128)
        itab[tid] = (tid < 64) ? p.source[sprev * BSZ + tid] : p.target[sprev * BSZ + (tid - 64)];
    const float* xs = p.x + (size_t)(snext * BSZ + b) * NN;
    const float* ts = p.t + (size_t)(snext * BSZ + b) * NN;
    if (tid == 0) msg[0] = xs[idx];
    if (tid < 128) {
        float tv = ts[idx];
        msg[1 + tid] = __cosf(tv * p.tw[tid] + p.tb_[tid]);
    }
    __syncthreads();
    int w = -1;
    if (sprev >= 0) {
        for (int k = 127; k >= 0; --k) if (itab[k] == idx) { w = k; break; }
    }
    if (tid < 128) {
        h[tid] = zeroH ? 0.f
               : (w >= 0 ? p.newh[par ^ 1][w * LAT + tid] : p.mem[(size_t)idx * LAT + tid]);
    }
    __syncthreads();
    if (tid < 128) {
        int j = tid;
        float a0 = p.b_ih[j], a1 = p.b_ih[128 + j], a2 = p.b_ih[256 + j];
#pragma unroll 4
        for (int d = 0; d < 129; ++d) {
            float m = msg[d];
            const float* col = p.W_ihT + d * 384;
            a0 += m * col[j]; a1 += m * col[128 + j]; a2 += m * col[256 + j];
        }
        gi3[j] = a0; gi3[128 + j] = a1; gi3[256 + j] = a2;
    } else {
        int j = tid - 128;
        float a0 = p.b_hh[j], a1 = p.b_hh[128 + j], a2 = p.b_hh[256 + j];
#pragma unroll 4
        for (int l = 0; l < 128; ++l) {
            float hv = h[l];
            const float* col = p.W_hhT + l * 384;
            a0 += hv * col[j]; a1 += hv * col[128 + j]; a2 += hv * col[256 + j];
        }
        gh3[j] = a0; gh3[128 + j] = a1; gh3[256 + j] = a2;
    }
    __syncthreads();
    if (tid < 128) {
        int j = tid;
        float rr = 1.f / (1.f + __expf(-(gi3[j] + gh3[j])));
        float zz = 1.f / (1.f + __expf(-(gi3[128 + j] + gh3[128 + j])));
        float nn2 = tanhf(gi3[256 + j] + rr * gh3[256 + j]);
        float val = (1.f - zz) * nn2 + zz * h[j];
        hn[j] = val;
        p.newh[par][r * LAT + j] = val;
    }
    if (r < 64) return;

    // ---------------- A(snext) for {b2 : s_last(b2) == r-64} ----------------
    int rT = r - 64;
    int* tg = itab;   // reuse
    __syncthreads();
    if (tid < 64) tg[tid] = p.target[snext * BSZ + tid];
    __syncthreads();
    unsigned long long mask = 0;
    if (tid < 64) {
        int myt = tg[tid]; int sl = 0;
        for (int k = 0; k < 64; ++k) if (tg[k] == myt) sl = k;
        mask = __ballot(sl == rT);
    }
    if (tid == 0) *amask = mask;
    __syncthreads();
    unsigned long long bl = *amask;
    float* u0qb = p.u0qbk[par];
    float* uTb  = p.uT[par];
    float* ftb  = p.ftab[par];
    while (bl) {
        int b2 = __ffsll((long long)bl) - 1; bl &= bl - 1;
        if (tid == 0) *axv = p.x[(size_t)(snext * BSZ + b2) * NN + tg[b2]];
        __syncthreads();
        float xv = *axv;
        {   // u[d] = uc[d] + xv*kw0[d] + hn . BT[:,d]; thread d (tid==0 also d=256)
            int d = tid;
            float a0 = 0.f, a1 = 0.f;
#pragma unroll 4
            for (int l = 0; l < 128; l += 2) {
                a0 += hn[l] * p.BT[l * 260 + d];
                a1 += hn[l + 1] * p.BT[(l + 1) * 260 + d];
            }
            float a = p.uc[d] + xv * p.kw0[d] + a0 + a1;
            if (d == 0) u0qb[b2] = a;
            else if (d <= 128) uTb[(d - 1) * BSZ + b2] = a;
            else udt[d - 129] = a;
            if (tid == 0) {
                float c0 = 0.f, c1 = 0.f;
#pragma unroll 4
                for (int l = 0; l < 128; l += 2) {
                    c0 += hn[l] * p.BT[l * 260 + 256];
                    c1 += hn[l + 1] * p.BT[(l + 1) * 260 + 256];
                }
                udt[127] = p.uc[256] + xv * p.kw0[256] + c0 + c1;
            }
        }
        if (tid >= 192) {   // qbk
            int i = tid - 192;
            float a = hn[i] * p.abk[i] + hn[64 + i] * p.abk[64 + i];
            for (int off = 32; off; off >>= 1) a += __shfl_down(a, off, 64);
            if (i == 0) u0qb[64 + b2] = p.scal[0] + xv * p.scal[1] + a;
        }
        __syncthreads();
        {   // ftab: 8 points/thread, L split 2 ways
            int pi = tid & 127, lc = tid >> 7;
            int l0 = lc * 64;
            float a0x = 0.f, a0y = 0.f, a0z = 0.f, a0w = 0.f;
            float a1x = 0.f, a1y = 0.f, a1z = 0.f, a1w = 0.f;
#pragma unroll 4
            for (int l = l0; l < l0 + 64; ++l) {
                float ul = udt[l];
                const float* cp = &p.costab[l * CSTRIDE + pi * 8];
                float4 c0 = *(const float4*)cp;
                float4 c1 = *(const float4*)(cp + 4);
                a0x += ul * c0.x; a0y += ul * c0.y; a0z += ul * c0.z; a0w += ul * c0.w;
                a1x += ul * c1.x; a1y += ul * c1.y; a1z += ul * c1.z; a1w += ul * c1.w;
            }
            if (lc) {
                float* fp = &fpart[pi * 8];
                *(float4*)fp = make_float4(a0x, a0y, a0z, a0w);
                *(float4*)(fp + 4) = make_float4(a1x, a1y, a1z, a1w);
            }
            if (pi == 127) {
                float a = 0.f;
                for (int l = l0; l < l0 + 64; ++l) a += udt[l] * p.costab[l * CSTRIDE + KTAB];
                red2[lc] = a;
            }
            __syncthreads();
            if (lc == 0) {
                const float* fp = &fpart[pi * 8];
                a0x += fp[0]; a0y += fp[1]; a0z += fp[2]; a0w += fp[3];
                a1x += fp[4]; a1y += fp[5]; a1z += fp[6]; a1w += fp[7];
                float* fo = &ftb[b2 * FSTRIDE + pi * 8];
                *(float4*)fo = make_float4(a0x, a0y, a0z, a0w);
                *(float4*)(fo + 4) = make_float4(a1x, a1y, a1z, a1w);
            }
            if (tid == 0) ftb[b2 * FSTRIDE + KTAB] = red2[0] + red2[1];
        }
        __syncthreads();
    }
}

// ============================================================================================
// combine for one batch element, 256 threads
// ============================================================================================
__device__ void combine256(const float* __restrict__ partials, const float* __restrict__ vconst,
                           float* __restrict__ out, float* sm, int b, int ps) {
    int tid = threadIdx.x;
    float m = -3.0e38f, d = 0.f, n = 0.f;
    if (tid < NTILES) {
        float4 v = *((const float4*)partials + b * NTILES + tid);
        m = v.x; d = v.y; n = v.z;
    }
#pragma unroll
    for (int off = 32; off; off >>= 1) {
        float mo = __shfl_down(m, off, 64);
        float d2 = __shfl_down(d, off, 64);
        float n2 = __shfl_down(n, off, 64);
        float M = fmaxf(m, mo);
        float e1 = __expf(m - M), e2 = __expf(mo - M);
        d = d * e1 + d2 * e2; n = n * e1 + n2 * e2; m = M;
    }
    float* red = sm;
    int w = tid >> 6;
    if ((tid & 63) == 0) { red[w * 3] = m; red[w * 3 + 1] = d; red[w * 3 + 2] = n; }
    __syncthreads();
    if (tid == 0) {
        float M = red[0], D = red[1], Nm = red[2];
        for (int k2 = 1; k2 < 4; ++k2) {
            float m2 = red[k2 * 3], d2 = red[k2 * 3 + 1], n2 = red[k2 * 3 + 2];
            float M2 = fmaxf(M, m2);
            float e1 = __expf(M - M2), e2 = __expf(m2 - M2);
            D = D * e1 + d2 * e2; Nm = Nm * e1 + n2 * e2; M = M2;
        }
        out[ps * BSZ + b] = Nm / D + vconst[0];
    }
}

// ============================================================================================
// setup: transposes + costab + wv_out/vconst/mode + BT/kw0/uc/abk/scal  (qconst recomputed
// locally where needed). Grid 388.
// ============================================================================================
__global__ __launch_bounds__(256) void setup_kernel(KP p) {
    int blk = blockIdx.x, tid = threadIdx.x;
    __shared__ float sm[256];
    if (blk < 256) {
        int gtid = blk * 256 + tid;
        const int GS = 256 * 256;
        for (int i = gtid; i < 129 * 384; i += GS) { int d = i / 384, j = i % 384; p.W_ihT[i] = p.W_ih[j * 129 + d]; }
        for (int i = gtid; i < 128 * 384; i += GS) { int l = i / 384, j = i % 384; p.W_hhT[i] = p.W_hh[j * 128 + l]; }
        for (int pp = gtid; pp <= KTAB; pp += GS) {
            float tv = (float)pp * (1.0f / KTAB);
            for (int l = 0; l < 128; ++l) p.costab[l * CSTRIDE + pp] = __cosf(tv * p.tw[l] + p.tb_[l]);
        }
    } else if (blk == 256) {
        for (int d = tid; d < DH; d += 256) {
            float a = 0.f;
            for (int j = 0; j < LAT; ++j) a += p.Wv[d * LAT + j] * p.W_out[j];
            p.wv_out[d] = a;
        }
        if (tid == 0) {
            float a = p.b_out[0];
            for (int j = 0; j < LAT; ++j) a += p.bv[j] * p.W_out[j];
            p.vconst[0] = a;
        }
        __shared__ int hasHigh, hasFloat;
        if (tid == 0) { hasHigh = 0; hasFloat = 0; }
        __syncthreads();
        const int* mask = (const int*)p.maskp;
        for (int i = tid; i < 4096; i += 256) {
            int v = mask[i];
            if ((unsigned)v > 1u) atomicOr(&hasHigh, 1);
            if (v == 0x3F800000) atomicOr(&hasFloat, 1);
        }
        __syncthreads();
        if (tid == 0) p.modep[0] = hasFloat ? 2 : (hasHigh ? 1 : 0);
    } else if (blk < 385) {          // BT row l
        int l = blk - 257;
        float* vrow = sm;
        if (tid < 128) vrow[tid] = p.Wq[(1 + l) * LAT + tid];
        __syncthreads();
        for (int d = tid; d < DH; d += 256) {
            const float* wkr = p.Wk + d * LAT;
            float a = 0.f;
#pragma unroll 4
            for (int j = 0; j < 128; ++j) a += wkr[j] * vrow[j];
            p.BT[l * 260 + d] = a;
        }
    } else if (blk == 385) {         // kw0 = Wk @ Wq[0,:]
        float* vrow = sm;
        if (tid < 128) vrow[tid] = p.Wq[tid];
        __syncthreads();
        for (int d = tid; d < DH; d += 256) {
            const float* wkr = p.Wk + d * LAT;
            float a = 0.f;
#pragma unroll 4
            for (int j = 0; j < 128; ++j) a += wkr[j] * vrow[j];
            p.kw0[d] = a;
        }
    } else if (blk == 386) {         // uc = Wk @ qconst (qconst recomputed)
        __shared__ float cosv[128], qc[128];
        if (tid < 128) cosv[tid] = __cosf(p.tb_[tid]);
        __syncthreads();
        if (tid < 128) {
            float a = p.bq[tid];
            for (int j = 0; j < 128; ++j) a += cosv[j] * p.Wq[(129 + j) * LAT + tid];
            qc[tid] = a;
        }
        __syncthreads();
        for (int d = tid; d < DH; d += 256) {
            const float* wkr = p.Wk + d * LAT;
            float a = 0.f;
#pragma unroll 4
            for (int j = 0; j < 128; ++j) a += wkr[j] * qc[j];
            p.uc[d] = a;
        }
    } else {                         // abk + scal
        __shared__ float bkv[128], cosv[128], tpart[128];
        if (tid < 128) { bkv[tid] = p.bk[tid]; cosv[tid] = __cosf(p.tb_[tid]); }
        __syncthreads();
        if (tid < 128) {
            const float* wqr = p.Wq + (1 + tid) * LAT;
            float a = 0.f;
#pragma unroll 4
            for (int j = 0; j < 128; ++j) a += wqr[j] * bkv[j];
            p.abk[tid] = a;
        } else {
            int j = tid - 128;
            const float* wqr = p.Wq + (129 + j) * LAT;
            float a = 0.f;
#pragma unroll 4
            for (int l = 0; l < 128; ++l) a += wqr[l] * bkv[l];
            tpart[j] = cosv[j] * a;
        }
        __syncthreads();
        if (tid == 0) {
            float s0 = 0.f, s1 = 0.f;
            for (int l = 0; l < 128; ++l) { s0 += p.bq[l] * bkv[l]; s1 += p.Wq[l] * bkv[l]; }
            for (int j = 0; j < 128; ++j) s0 += tpart[j];
            p.scal[0] = s0; p.scal[1] = s1;
        }
    }
}

// ============================================================================================
// pre: gtab (5 blocks) + gru(0)+A(0) (128 blocks). Grid 133.
// ============================================================================================
__global__ __launch_bounds__(256) void pre2_kernel(KP p) {
    __shared__ __align__(16) float sm[2464];
    int blk = blockIdx.x, tid = threadIdx.x;
    if (blk < 5) {
        __shared__ float wv_s[LAT];
        if (tid < LAT) wv_s[tid] = p.wv_out[129 + tid];
        __syncthreads();
        int pp = blk * 256 + tid;
        if (pp <= KTAB) {
            float a = 0.f;
            for (int l = 0; l < 128; ++l) a += wv_s[l] * p.costab[l * CSTRIDE + pp];
            p.gtab[pp] = a;
        }
        return;
    }
    gru_a_block(p, sm, blk - 5, /*snext=*/0, /*sprev=*/-1, /*zeroH=*/1);
}

// ============================================================================================
// step kernel: blocks 0..156 attn(s) [patched]; 157..284 gru(s+1)+A(s+1) [patched];
// 285 scatter(s); 286..349 combine(s-1). No intra-kernel cross-block deps.
// ============================================================================================
__global__ __launch_bounds__(256) void step_kernel(KP p, int s) {
    __shared__ __align__(16) float sm[9472];
    int blk = blockIdx.x, tid = threadIdx.x;
    int par = s & 1;

    if (blk >= 157 && blk < 285) {
        if (s < S_LEN - 1)
            gru_a_block(p, sm, blk - 157, /*snext=*/s + 1, /*sprev=*/s, /*zeroH=*/0);
        return;
    }
    if (blk == 285) {   // scatter(s): newh[par] -> mem (readers patch; no race)
        int* idxs  = (int*)sm;
        int* alive = idxs + 128;
        if (tid < 128) idxs[tid] = (tid < 64) ? p.source[s * BSZ + tid] : p.target[s * BSZ + (tid - 64)];
        __syncthreads();
        if (tid < 128) {
            int i2 = idxs[tid];
            int a = 1;
            for (int r2 = tid + 1; r2 < 128; ++r2)
                if (idxs[r2] == i2) { a = 0; break; }
            alive[tid] = a;
        }
        __syncthreads();
        int row = tid >> 1, q2 = tid & 1;
        if (alive[row]) {
            const float4* srcp = (const float4*)(p.newh[par] + row * LAT + q2 * 64);
            float4* dstp = (float4*)(p.mem + (size_t)idxs[row] * LAT + q2 * 64);
#pragma unroll
            for (int j = 0; j < 16; ++j) dstp[j] = srcp[j];
        }
        return;
    }
    if (blk >= 286) {   // combine(s-1)
        if (s > 0) combine256(p.partials[par ^ 1], p.vconst, p.out, sm, blk - 286, s - 1);
        return;
    }

    // ---------------- attn tile (round-0 logic + scatter patch) ----------------
    float* memT   = sm;           // 64*72
    float* uTs    = sm + 4608;    // 64*68
    float* memv_s = sm + 8960;    // 64
    float* wv_s   = sm + 9024;    // 128
    float* u0_s   = sm + 9152;    // 64
    float* qbk_s  = sm + 9216;    // 64
    int*   idxs   = (int*)(sm + 9280);   // 128
    int*   prow   = idxs + 128;          // 64
    int tile = blk;
    int n0 = tile * NTILE;
    int tb = tid >> 4, tn = tid & 15;
    int nvalid = NN - n0; if (nvalid > NTILE) nvalid = NTILE;

    if (tid < 128) wv_s[tid] = p.wv_out[1 + tid];
    if (tid < 64) {
        u0_s[tid] = p.u0qbk[par][tid];
        qbk_s[tid] = p.u0qbk[par][64 + tid];
        memv_s[tid] = 0.f;
    }
    if (tid < 128) idxs[tid] = (tid < 64) ? p.source[s * BSZ + tid] : p.target[s * BSZ + (tid - 64)];
    __syncthreads();
    if (tid < 64) {
        int node = n0 + tid; int w = -1;
        for (int k = 127; k >= 0; --k) if (idxs[k] == node) { w = k; break; }
        prow[tid] = w;
    }

    float acc[4][4];
#pragma unroll
    for (int i = 0; i < 4; ++i)
#pragma unroll
        for (int j = 0; j < 4; ++j) acc[i][j] = 0.f;

    const float* nh = p.newh[par];
    for (int l0 = 0; l0 < 128; l0 += 64) {
        __syncthreads();
        {   // stage mem (or patched newh row) -> memT transposed
            int n_l = tid & 63, lq = (tid >> 6) * 16;
            if (n_l < nvalid) {
                int w = prow[n_l];
                const float* mrow = (w >= 0) ? (nh + w * LAT + l0 + lq)
                                             : (p.mem + (size_t)(n0 + n_l) * LAT + l0 + lq);
                float4 a0 = *(const float4*)(mrow + 0);
                float4 a1 = *(const float4*)(mrow + 4);
                float4 a2 = *(const float4*)(mrow + 8);
                float4 a3 = *(const float4*)(mrow + 12);
                memT[(lq + 0) * 72 + n_l] = a0.x; memT[(lq + 1) * 72 + n_l] = a0.y;
                memT[(lq + 2) * 72 + n_l] = a0.z; memT[(lq + 3) * 72 + n_l] = a0.w;
                memT[(lq + 4) * 72 + n_l] = a1.x; memT[(lq + 5) * 72 + n_l] = a1.y;
                memT[(lq + 6) * 72 + n_l] = a1.z; memT[(lq + 7) * 72 + n_l] = a1.w;
                memT[(lq + 8) * 72 + n_l] = a2.x; memT[(lq + 9) * 72 + n_l] = a2.y;
                memT[(lq + 10) * 72 + n_l] = a2.z; memT[(lq + 11) * 72 + n_l] = a2.w;
                memT[(lq + 12) * 72 + n_l] = a3.x; memT[(lq + 13) * 72 + n_l] = a3.y;
                memT[(lq + 14) * 72 + n_l] = a3.z; memT[(lq + 15) * 72 + n_l] = a3.w;
            } else {
                for (int j = 0; j < 16; ++j) memT[(lq + j) * 72 + n_l] = 0.f;
            }
        }
        {   // stage uT chunk -> uTs
            int bq4 = (tid & 15) * 4;
            int ll = (tid >> 4) * 4;
            const float* uTb = p.uT[par];
            for (int j = 0; j < 4; ++j) {
                float4 v = *(const float4*)&uTb[(l0 + ll + j) * BSZ + bq4];
                *(float4*)&uTs[(ll + j) * 68 + bq4] = v;
            }
        }
        __syncthreads();
        if (tid < 64) {   // memv partial
            float a = memv_s[tid];
            for (int l = 0; l < 64; ++l) a += wv_s[l0 + l] * memT[l * 72 + tid];
            memv_s[tid] = a;
        }
        for (int l = 0; l < 64; ++l) {
            float4 uv = *(const float4*)&uTs[l * 68 + tb * 4];
            float4 mv = *(const float4*)&memT[l * 72 + tn * 4];
            acc[0][0] += uv.x * mv.x; acc[0][1] += uv.x * mv.y; acc[0][2] += uv.x * mv.z; acc[0][3] += uv.x * mv.w;
            acc[1][0] += uv.y * mv.x; acc[1][1] += uv.y * mv.y; acc[1][2] += uv.y * mv.z; acc[1][3] += uv.y * mv.w;
            acc[2][0] += uv.z * mv.x; acc[2][1] += uv.z * mv.y; acc[2][2] += uv.z * mv.z; acc[2][3] += uv.z * mv.w;
            acc[3][0] += uv.w * mv.x; acc[3][1] += uv.w * mv.y; acc[3][2] += uv.w * mv.z; acc[3][3] += uv.w * mv.w;
        }
    }
    __syncthreads();

    const float c0 = p.wv_out[0];
    int mode = p.modep[0];
    const int* m32 = (const int*)p.maskp;
    const unsigned char* m8 = (const unsigned char*)p.maskp;
    const float* mf = (const float*)p.maskp;
    const float* gtab = p.gtab;
    const float* ftb = p.ftab[par];

    float pm[4], pd[4], pn[4];
#pragma unroll
    for (int i = 0; i < 4; ++i) { pm[i] = -3.0e38f; pd[i] = 0.f; pn[i] = 0.f; }

    for (int i = 0; i < 4; ++i) {
        int b = tb * 4 + i;
        size_t base = (size_t)(s * BSZ + b) * NN + n0 + tn * 4;
        float xv4[4], tv4[4]; int msk[4], vld[4];
        if (tn * 4 + 3 < nvalid) {
            float4 xx = *(const float4*)(p.x + base);
            float4 tt = *(const float4*)(p.t + base);
            xv4[0] = xx.x; xv4[1] = xx.y; xv4[2] = xx.z; xv4[3] = xx.w;
            tv4[0] = tt.x; tv4[1] = tt.y; tv4[2] = tt.z; tv4[3] = tt.w;
            if (mode == 1) {
                unsigned mw = *(const unsigned*)(m8 + base);
                msk[0] = mw & 0xff; msk[1] = (mw >> 8) & 0xff; msk[2] = (mw >> 16) & 0xff; msk[3] = (mw >> 24) & 0xff;
            } else if (mode == 2) {
                float4 mm = *(const float4*)(mf + base);
                msk[0] = (mm.x != 0.f); msk[1] = (mm.y != 0.f); msk[2] = (mm.z != 0.f); msk[3] = (mm.w != 0.f);
            } else {
                int4 mm = *(const int4*)(m32 + base);
                msk[0] = mm.x; msk[1] = mm.y; msk[2] = mm.z; msk[3] = mm.w;
            }
            vld[0] = vld[1] = vld[2] = vld[3] = 1;
        } else {
            for (int j = 0; j < 4; ++j) {
                int n = tn * 4 + j;
                vld[j] = (n < nvalid);
                if (vld[j]) {
                    xv4[j] = p.x[base + j]; tv4[j] = p.t[base + j];
                    msk[j] = (mode == 1) ? (int)m8[base + j] : (mode == 2) ? (mf[base + j] != 0.f) : m32[base + j];
                } else { xv4[j] = 0.f; tv4[j] = 0.f; msk[j] = 0; }
            }
        }
        const float* ft = ftb + b * FSTRIDE;
#pragma unroll
        for (int j = 0; j < 4; ++j) {
            if (!vld[j]) continue;
            float xv = xv4[j], tv = tv4[j];
            float pq = tv * (float)KTAB;
            pq = fminf(fmaxf(pq, 0.f), (float)KTAB - 0.001f);
            int ii = (int)pq;
            float fr = pq - (float)ii;
            float f0 = ft[ii];
            float fv = f0 + (ft[ii + 1] - f0) * fr;
            float g0 = gtab[ii];
            float gv = g0 + (gtab[ii + 1] - g0) * fr;
            float sc = SCALE * (xv * u0_s[b] + acc[i][j] + fv + qbk_s[b]);
            if (msk[j] == 0) sc = NEG1E9;
            float val = xv * c0 + memv_s[tn * 4 + j] + gv;
            if (sc > pm[i]) {
                float a = __expf(pm[i] - sc);
                pd[i] = pd[i] * a + 1.f;
                pn[i] = pn[i] * a + val;
                pm[i] = sc;
            } else {
                float e = __expf(sc - pm[i]);
                pd[i] += e;
                pn[i] += e * val;
            }
        }
    }
#pragma unroll
    for (int mk2 = 1; mk2 < 16; mk2 <<= 1) {
#pragma unroll
        for (int i = 0; i < 4; ++i) {
            float mo = __shfl_xor(pm[i], mk2);
            float d2 = __shfl_xor(pd[i], mk2);
            float n2 = __shfl_xor(pn[i], mk2);
            float M = fmaxf(pm[i], mo);
            float e1 = __expf(pm[i] - M), e2 = __expf(mo - M);
            pd[i] = pd[i] * e1 + d2 * e2;
            pn[i] = pn[i] * e1 + n2 * e2;
            pm[i] = M;
        }
    }
    if (tn == 0) {
#pragma unroll
        for (int i = 0; i < 4; ++i) {
            int b = tb * 4 + i;
            *(float4*)&p.partials[par][(size_t)(b * NTILES + tile) * 4] = make_float4(pm[i], pd[i], pn[i], 0.f);
        }
    }
}

// ============================================================================================
__global__ __launch_bounds__(256) void tail2_kernel(KP p) {
    __shared__ float sm[16];
    combine256(p.partials[(S_LEN - 1) & 1], p.vconst, p.out, sm, blockIdx.x, S_LEN - 1);
}

extern "C" void kernel_launch(void* const* d_in, const int* in_sizes, int n_in,
                              void* d_out, int out_size, void* d_ws, size_t ws_size,
                              hipStream_t stream) {
    KP kp;
    kp.x      = (const float*)d_in[0];
    kp.t      = (const float*)d_in[1];
    kp.source = (const int*)d_in[2];
    kp.target = (const int*)d_in[3];
    kp.maskp  = (const void*)d_in[4];
    kp.tw     = (const float*)d_in[5];
    kp.tb_    = (const float*)d_in[6];
    kp.W_ih   = (const float*)d_in[7];
    kp.W_hh   = (const float*)d_in[8];
    kp.b_ih   = (const float*)d_in[9];
    kp.b_hh   = (const float*)d_in[10];
    kp.Wq     = (const float*)d_in[11];
    kp.bq     = (const float*)d_in[12];
    kp.Wk     = (const float*)d_in[13];
    kp.bk     = (const float*)d_in[14];
    kp.Wv     = (const float*)d_in[15];
    kp.bv     = (const float*)d_in[16];
    kp.W_out  = (const float*)d_in[17];
    kp.b_out  = (const float*)d_in[18];
    kp.out    = (float*)d_out;

    float* w = (float*)d_ws;
    kp.mem        = w; w += (size_t)NN * LAT;       // 1,280,000
    kp.newh[0]    = w; w += 128 * LAT;
    kp.newh[1]    = w; w += 128 * LAT;
    kp.uT[0]      = w; w += LAT * BSZ;
    kp.uT[1]      = w; w += LAT * BSZ;
    kp.u0qbk[0]   = w; w += 128;
    kp.u0qbk[1]   = w; w += 128;
    kp.ftab[0]    = w; w += BSZ * FSTRIDE;
    kp.ftab[1]    = w; w += BSZ * FSTRIDE;
    kp.partials[0] = w; w += (size_t)BSZ * NTILES * 4;
    kp.partials[1] = w; w += (size_t)BSZ * NTILES * 4;
    kp.gtab       = w; w += 1056;
    kp.costab     = w; w += LAT * CSTRIDE;          // 132,096
    kp.wv_out     = w; w += 288;
    kp.vconst     = w; w += 32;
    kp.W_ihT      = w; w += 129 * 384;
    kp.W_hhT      = w; w += 128 * 384;
    kp.BT         = w; w += 128 * 260;
    kp.uc         = w; w += 288;
    kp.kw0        = w; w += 288;
    kp.abk        = w; w += 128;
    kp.scal       = w; w += 32;
    kp.modep      = (int*)w; w += 32;

    hipMemsetAsync(kp.mem, 0, (size_t)NN * LAT * sizeof(float), stream);
    setup_kernel<<<388, 256, 0, stream>>>(kp);
    pre2_kernel<<<133, 256, 0, stream>>>(kp);
    for (int s = 0; s < S_LEN; ++s)
        step_kernel<<<STEP_BLKS, 256, 0, stream>>>(kp, s);
    tail2_kernel<<<64, 256, 0, stream>>>(kp);
}